// Round 2
// baseline (1626.451 us; speedup 1.0000x reference)
//
#include <hip/hip_runtime.h>

#define N_NODES 50000
#define N_EDGES 800000
#define C_MSG 200

typedef __bf16 bf16;
typedef __attribute__((ext_vector_type(8))) __bf16 bf16x8;
typedef __attribute__((ext_vector_type(4))) float f32x4;

static __device__ __forceinline__ unsigned int pk_bf16(float a, float b) {
    union { bf16 h[2]; unsigned int u; } cv;
    cv.h[0] = (bf16)a; cv.h[1] = (bf16)b;
    return cv.u;
}

// ===========================================================================
// Weight packers (device fns) -> MFMA B-frag order (16x16x32), biases folded.
// Fragment f at out[f*512 + lane*8 + i]; lane holds B[k][n], k=kt*32+(lane>>4)*8+i.
// Paired N-tiles: pair p covers cols p*32 + 2*(lane&15) + parity.
// ===========================================================================
static __device__ void dev_pack_wm1(int tid, const float* W, const float* bm1,
                                    bf16* out) {
    int i = tid & 7, lane = (tid >> 3) & 63, rest = tid >> 9;
    int kt = rest % 2, t = rest / 2;
    int k = kt * 32 + ((lane >> 4) * 8) + i;
    int c = lane & 15;
    int n = (t < 12) ? ((t >> 1) * 32 + 2 * c + (t & 1)) : (192 + c);
    float v = 0.f;
    if (n < C_MSG) {
        if (k < 30)       v = W[k * C_MSG + n];
        else if (k == 30) v = bm1[n];
        else if (k >= 32) v = W[(k - 2) * C_MSG + n];
    }
    out[tid] = (bf16)v;
}

static __device__ void dev_pack_wm2(int tid, const float* W, const float* bm2,
                                    bf16* out) {
    int i = tid & 7, lane = (tid >> 3) & 63, rest = tid >> 9;
    int kt = rest % 7, nt = rest / 7;
    int k = kt * 32 + ((lane >> 4) * 8) + i;
    int n = 2 * (lane & 15) + nt;
    float v = 0.f;
    if (n < 30) {
        if (k < C_MSG)       v = W[k * 30 + n];
        else if (k == C_MSG) v = bm2[n];
    }
    out[tid] = (bf16)v;
}

static __device__ void dev_pack_w2h(int tid, const float* W, const float* b2,
                                    bf16* out) {
    int i = tid & 7, lane = (tid >> 3) & 63, nt = tid >> 9;
    int k = ((lane >> 4) * 8) + i;
    int n = 2 * (lane & 15) + nt;
    float v = 0.f;
    if (n < 30) {
        if (k < 30)       v = W[k * 30 + n];
        else if (k == 30) v = b2[n];
    }
    out[tid] = (bf16)v;
}

static __device__ void dev_pack_w2o(int tid, const float* W, const float* b2,
                                    bf16* out) {
    int i = tid & 7, lane = (tid >> 3) & 63;
    int k = ((lane >> 4) * 8) + i;
    int n = lane & 15;
    float v = 0.f;
    if (n == 0) {
        if (k < 30)       v = W[k];
        else if (k == 30) v = b2[0];
    }
    out[tid] = (bf16)v;
}

static __device__ void dev_pack_sel(int tid, bf16* out) {
    int i = tid & 7, lane = (tid >> 3) & 63, f = tid >> 9;
    int kt = f >> 1, nt = f & 1;
    int kloc = ((lane >> 4) * 8) + i;
    int n = 2 * (lane & 15) + nt;
    float v = (kloc == n && n < 30) ? ((kt & 1) ? -1.f : 1.f) : 0.f;
    out[tid] = (bf16)v;
}

// ===========================================================================
// setup_a: count (3125 blocks) + pack_all (186) + node_d (196) in ONE dispatch
// ===========================================================================
__global__ __launch_bounds__(256) void setup_a(
    const int* __restrict__ dst, int* __restrict__ counts,
    const float* __restrict__ Wm1_h, const float* __restrict__ bm1_h,
    const float* __restrict__ Wm1_o, const float* __restrict__ bm1_o,
    const float* __restrict__ Wm2_h, const float* __restrict__ bm2_h,
    const float* __restrict__ Wm2_o, const float* __restrict__ bm2_o,
    const float* __restrict__ W2_h,  const float* __restrict__ b2_h,
    const float* __restrict__ W2_o,  const float* __restrict__ b2_o,
    const float* __restrict__ Wm1_d,
    bf16* __restrict__ Wm1B_h, bf16* __restrict__ Wm1B_o,
    bf16* __restrict__ Wm2B_h, bf16* __restrict__ Wm2B_o,
    bf16* __restrict__ W2B_h,  bf16* __restrict__ W2B_o,
    bf16* __restrict__ SelB,   float* __restrict__ Wm1T_d,
    const float* __restrict__ features, const float* __restrict__ W1_d,
    const float* __restrict__ b1_d, float* __restrict__ bufA) {
    int b = blockIdx.x, t = threadIdx.x;
    if (b < 3125) {                                  // count
        int e = b * 256 + t;
        if (e < N_EDGES) atomicAdd(&counts[dst[e]], 1);
    } else if (b < 3311) {                           // pack_all
        int pb = b - 3125;
        if (pb < 52)       dev_pack_wm1(pb * 256 + t, Wm1_h, bm1_h, Wm1B_h);
        else if (pb < 104) dev_pack_wm1((pb - 52) * 256 + t, Wm1_o, bm1_o, Wm1B_o);
        else if (pb < 132) dev_pack_wm2((pb - 104) * 256 + t, Wm2_h, bm2_h, Wm2B_h);
        else if (pb < 160) dev_pack_wm2((pb - 132) * 256 + t, Wm2_o, bm2_o, Wm2B_o);
        else if (pb < 164) dev_pack_w2h((pb - 160) * 256 + t, W2_h, b2_h, W2B_h);
        else if (pb < 166) dev_pack_w2o((pb - 164) * 256 + t, W2_o, b2_o, W2B_o);
        else if (pb < 182) dev_pack_sel((pb - 166) * 256 + t, SelB);
        else {
            int i = (pb - 182) * 256 + t;
            if (i < C_MSG * 4) Wm1T_d[i] = Wm1_d[(i & 3) * C_MSG + (i >> 2)];
        }
    } else {                                         // node term, layer d
        int n = (b - 3311) * 256 + t;
        if (n < N_NODES) {
            float xv = features[n];
            for (int o = 0; o < 30; ++o)
                bufA[n * 30 + o] = fmaf(xv, W1_d[o], b1_d[o]);
        }
    }
}

// Parallel scan over counts
__global__ __launch_bounds__(256) void scan_kernel(const int* __restrict__ counts,
                                                   int* __restrict__ offsets,
                                                   int* __restrict__ cursor) {
    __shared__ int ws[4];
    const int b = blockIdx.x, t = threadIdx.x;
    const int lane = t & 63, wv = t >> 6;
    int acc = 0;
    for (int i = t; i < b * 256; i += 256) acc += counts[i];
#pragma unroll
    for (int d = 32; d > 0; d >>= 1) acc += __shfl_xor(acc, d);
    if (lane == 0) ws[wv] = acc;
    __syncthreads();
    int base = ws[0] + ws[1] + ws[2] + ws[3];
    __syncthreads();
    int i = b * 256 + t;
    int v = (i < N_NODES) ? counts[i] : 0;
    int inc = v;
#pragma unroll
    for (int d = 1; d < 64; d <<= 1) {
        int u = __shfl_up(inc, d);
        if (lane >= d) inc += u;
    }
    if (lane == 63) ws[wv] = inc;
    __syncthreads();
    int waveoff = 0;
    for (int k = 0; k < wv; ++k) waveoff += ws[k];
    int excl = base + waveoff + inc - v;
    if (i < N_NODES) { offsets[i] = excl; cursor[i] = excl; }
    if (i == N_NODES - 1) offsets[N_NODES] = excl + v;
}

// scatter: ONE int4 stream {src, dst, ewbf, perm} in perm order
__global__ __launch_bounds__(256) void scatter_kernel(
    const int* __restrict__ src, const int* __restrict__ dst,
    const float* __restrict__ ew, int* __restrict__ cursor,
    int4* __restrict__ edata) {
    int e = blockIdx.x * 256 + threadIdx.x;
    if (e < N_EDGES) {
        int d = dst[e];
        int p = atomicAdd(&cursor[d], 1);
        edata[p] = make_int4(src[e], d, (int)pk_bf16(ew[2 * e], ew[2 * e + 1]), e);
    }
}

// ===========================================================================
// Layer-d edge kernel (CIN=1): full-fp32 VALU path, perm order
// ===========================================================================
__global__ __launch_bounds__(256) void edge_d_kernel(
    const float* __restrict__ x, const int4* __restrict__ edata,
    const float* __restrict__ ew,
    const float* __restrict__ Wm1T, const float* __restrict__ bm1,
    const float* __restrict__ Wm2, const float* __restrict__ bm2,
    const float* __restrict__ W2, const float* __restrict__ b2, bf16* __restrict__ msg)
{
    int t = blockIdx.x * 256 + threadIdx.x;
    int4 ed = edata[t];
    float xi = x[ed.y], xj = x[ed.x];
    int p = ed.w;
    float e0 = ew[2 * p], e1 = ew[2 * p + 1];
    float m = bm2[0];
    for (int j = 0; j < C_MSG; ++j) {
        const float* __restrict__ wr = Wm1T + j * 4;
        float h = bm1[j];
        h = fmaf(xi, wr[0], h);
        h = fmaf(xj, wr[1], h);
        h = fmaf(e0, wr[2], h);
        h = fmaf(e1, wr[3], h);
        h = fmaxf(h, 0.f);
        m = fmaf(h, Wm2[j], m);
    }
    float md = m * (xi - xj);
    for (int o = 0; o < 15; ++o) {
        float f0 = fmaf(md, W2[2 * o], b2[2 * o]);
        float f1 = fmaf(md, W2[2 * o + 1], b2[2 * o + 1]);
        *(unsigned int*)(msg + (size_t)t * 32 + 2 * o) = pk_bf16(f0, f1);
    }
}

// ===========================================================================
// MFMA edge kernel v10: v9 (M-split, no barrier) + software pipelining.
//  R1 post-mortem: FETCH 66MB is edata 12.8MB + 8-XCD-replicated x gathers
//  (~51MB; x working set 6.4MB > 4MB per-XCD L2 -> thrash). Kernel is
//  LATENCY-bound on the serial per-tile chain (edata -> x gather -> MFMA ->
//  LDS -> MFMA -> store) with only ~3-5 waves/SIMD to hide it.
//  v10:
//   (1) T=4 tiles per wave (grid /4): all 4 edata loads upfront; x-frags for
//       tile t+1 prefetched before tile t's compute -> one tile's ~1000cyc
//       of compute hides the next tile's gather latency INSIDE the wave.
//       LDS region (16 rows/wave) reused across tiles; pad cols written once.
//       ed.z patch deferred to consume-time so prefetch is pure loads.
//   (2) xbf/xlo merged into ONE xc[node][64] row (hi cols 0-31, lo 32-63):
//       every random src gather now uses 100% of its fetched line(s)
//       (previously 2 arrays -> 2 lines touched, half of each used).
//   (3) __launch_bounds__(256,4): 128-VGPR budget for the pipeline.
//  MFMA sequence, relu/pack, store addresses per edge unchanged ->
//  bit-identical output to v9.
// ===========================================================================
struct Frags { bf16x8 A0, A1, a2, a3; };

static __device__ __forceinline__ void load_frags(const bf16* __restrict__ xc,
                                                  int4 ed, int quad, Frags& f) {
    const bf16* rd = xc + (size_t)ed.y * 64 + quad * 8;
    const bf16* rs = xc + (size_t)ed.x * 64 + quad * 8;
    f.A0 = *(const bf16x8*)(rd);
    f.a2 = *(const bf16x8*)(rd + 32);
    f.A1 = *(const bf16x8*)(rs);
    f.a3 = *(const bf16x8*)(rs + 32);
}

template<int COUT>
static __device__ __forceinline__ void compute_tile(
    const Frags& f, int4 ed, bf16* __restrict__ hp,
    int myrow, int col, int quad, int row0, int lane, int ebase,
    const bf16* __restrict__ Wm1B, const bf16* __restrict__ SelB,
    const bf16* __restrict__ Wm2B, const bf16* __restrict__ W2B,
    bf16* __restrict__ msg)
{
    bf16x8 A0 = f.A0, A1 = f.A1, a2 = f.a2, a3 = f.a3;
    // ew patch (rows 30/31 of the src slot) applied at consume time
    if (quad == 3) {
        union { unsigned int u; bf16 b[2]; } cv;
        cv.u = (unsigned int)ed.z;
        A1[6] = cv.b[0];
        A1[7] = cv.b[1];
    }

    // ---- diff[16x32] = (hi_d - hi_s) + (lo_d - lo_s) via selector GEMM ----
    // (selector rows 30/31 of the A1 slot are zero -> ew patch never reaches
    //  the diff)
    f32x4 dc0 = {0.f, 0.f, 0.f, 0.f}, dc1 = {0.f, 0.f, 0.f, 0.f};
    {
        bf16x8 b;
        b = *(const bf16x8*)(SelB + (size_t)0 * 512 + lane * 8);
        dc0 = __builtin_amdgcn_mfma_f32_16x16x32_bf16(A0, b, dc0, 0, 0, 0);
        b = *(const bf16x8*)(SelB + (size_t)1 * 512 + lane * 8);
        dc1 = __builtin_amdgcn_mfma_f32_16x16x32_bf16(A0, b, dc1, 0, 0, 0);
        b = *(const bf16x8*)(SelB + (size_t)2 * 512 + lane * 8);
        dc0 = __builtin_amdgcn_mfma_f32_16x16x32_bf16(A1, b, dc0, 0, 0, 0);
        b = *(const bf16x8*)(SelB + (size_t)3 * 512 + lane * 8);
        dc1 = __builtin_amdgcn_mfma_f32_16x16x32_bf16(A1, b, dc1, 0, 0, 0);
        b = *(const bf16x8*)(SelB + (size_t)4 * 512 + lane * 8);
        dc0 = __builtin_amdgcn_mfma_f32_16x16x32_bf16(a2, b, dc0, 0, 0, 0);
        b = *(const bf16x8*)(SelB + (size_t)5 * 512 + lane * 8);
        dc1 = __builtin_amdgcn_mfma_f32_16x16x32_bf16(a2, b, dc1, 0, 0, 0);
        b = *(const bf16x8*)(SelB + (size_t)6 * 512 + lane * 8);
        dc0 = __builtin_amdgcn_mfma_f32_16x16x32_bf16(a3, b, dc0, 0, 0, 0);
        b = *(const bf16x8*)(SelB + (size_t)7 * 512 + lane * 8);
        dc1 = __builtin_amdgcn_mfma_f32_16x16x32_bf16(a3, b, dc1, 0, 0, 0);
    }

    // ---- GEMM1 (M-split): own 16 edges, ALL 6 N-pairs + leftover tile ----
#pragma unroll
    for (int p = 0; p < 6; ++p) {
        const bf16* Wf = Wm1B + (size_t)(4 * p) * 512 + lane * 8;
        bf16x8 be0 = *(const bf16x8*)(Wf);
        bf16x8 be1 = *(const bf16x8*)(Wf + 512);
        bf16x8 bo0 = *(const bf16x8*)(Wf + 1024);
        bf16x8 bo1 = *(const bf16x8*)(Wf + 1536);
        f32x4 ae = {0.f, 0.f, 0.f, 0.f}, ao = {0.f, 0.f, 0.f, 0.f};
        ae = __builtin_amdgcn_mfma_f32_16x16x32_bf16(A0, be0, ae, 0, 0, 0);
        ae = __builtin_amdgcn_mfma_f32_16x16x32_bf16(A1, be1, ae, 0, 0, 0);
        ao = __builtin_amdgcn_mfma_f32_16x16x32_bf16(A0, bo0, ao, 0, 0, 0);
        ao = __builtin_amdgcn_mfma_f32_16x16x32_bf16(A1, bo1, ao, 0, 0, 0);
#pragma unroll
        for (int rg = 0; rg < 4; ++rg) {
            unsigned int u = pk_bf16(fmaxf(ae[rg], 0.f), fmaxf(ao[rg], 0.f));
            *(unsigned int*)(hp + (myrow + row0 + rg) * 232 +
                             p * 32 + 2 * col) = u;
        }
    }
    {   // leftover N-tile 12: cols 192..199 real
        const bf16* Wf = Wm1B + (size_t)24 * 512 + lane * 8;
        bf16x8 b0 = *(const bf16x8*)(Wf);
        bf16x8 b1 = *(const bf16x8*)(Wf + 512);
        f32x4 acc = {0.f, 0.f, 0.f, 0.f};
        acc = __builtin_amdgcn_mfma_f32_16x16x32_bf16(A0, b0, acc, 0, 0, 0);
        acc = __builtin_amdgcn_mfma_f32_16x16x32_bf16(A1, b1, acc, 0, 0, 0);
        if (col < 8) {
#pragma unroll
            for (int rg = 0; rg < 4; ++rg)
                hp[(myrow + row0 + rg) * 232 + 192 + col] =
                    (bf16)fmaxf(acc[rg], 0.f);
        }
    }

    // NO __syncthreads: h rows [myrow, myrow+16) written entirely by this
    // wave; per-wave ds ordering via lgkmcnt.

    // ---- GEMM2 on OWN 16 edges: h[16x224] @ Wm2[224x32]; md = m*diff ----
    f32x4 m0 = {0.f, 0.f, 0.f, 0.f}, m1 = {0.f, 0.f, 0.f, 0.f};
#pragma unroll
    for (int kt = 0; kt < 7; ++kt) {
        bf16x8 a = *(const bf16x8*)(hp + (myrow + col) * 232 + kt * 32 + quad * 8);
        bf16x8 b0 = *(const bf16x8*)(Wm2B + (size_t)kt * 512 + lane * 8);
        bf16x8 b1 = *(const bf16x8*)(Wm2B + (size_t)(7 + kt) * 512 + lane * 8);
        m0 = __builtin_amdgcn_mfma_f32_16x16x32_bf16(a, b0, m0, 0, 0, 0);
        m1 = __builtin_amdgcn_mfma_f32_16x16x32_bf16(a, b1, m1, 0, 0, 0);
    }
    // md overwrites OWN h rows, cols 0-31 (dead after own GEMM2; wave-local)
#pragma unroll
    for (int rg = 0; rg < 4; ++rg) {
        unsigned int u = (col == 15) ? pk_bf16(1.f, 0.f)
                                     : pk_bf16(m0[rg] * dc0[rg], m1[rg] * dc1[rg]);
        *(unsigned int*)(hp + (myrow + row0 + rg) * 232 + 2 * col) = u;
    }

    // ---- GEMM3: md[16x32] @ W2[32xN] -> msg (wave-local) ----
    bf16x8 am = *(const bf16x8*)(hp + (myrow + col) * 232 + quad * 8);
    if (COUT == 30) {
        bf16x8 b0 = *(const bf16x8*)(W2B + lane * 8);
        bf16x8 b1 = *(const bf16x8*)(W2B + 512 + lane * 8);
        f32x4 c0 = {0.f, 0.f, 0.f, 0.f}, c1 = {0.f, 0.f, 0.f, 0.f};
        c0 = __builtin_amdgcn_mfma_f32_16x16x32_bf16(am, b0, c0, 0, 0, 0);
        c1 = __builtin_amdgcn_mfma_f32_16x16x32_bf16(am, b1, c1, 0, 0, 0);
#pragma unroll
        for (int rg = 0; rg < 4; ++rg)
            *(unsigned int*)(msg + (size_t)(ebase + row0 + rg) * 32 + 2 * col) =
                pk_bf16(c0[rg], c1[rg]);
    } else {
        // COUT=1: compact msg1[e] layout — one 8B store per col==0 lane
        bf16x8 b0 = *(const bf16x8*)(W2B + lane * 8);
        f32x4 c0 = {0.f, 0.f, 0.f, 0.f};
        c0 = __builtin_amdgcn_mfma_f32_16x16x32_bf16(am, b0, c0, 0, 0, 0);
        if (col == 0) {
            union { bf16 h[4]; unsigned long long u; } pk4;
#pragma unroll
            for (int rg = 0; rg < 4; ++rg) pk4.h[rg] = (bf16)c0[rg];
            *(unsigned long long*)(msg + (ebase + row0)) = pk4.u;
        }
    }
}

template<int COUT>
__global__ __launch_bounds__(256, 4) void edge_mfma(
    const bf16* __restrict__ xc, const int4* __restrict__ edata,
    const bf16* __restrict__ Wm1B, const bf16* __restrict__ SelB,
    const bf16* __restrict__ Wm2B, const bf16* __restrict__ W2B,
    bf16* __restrict__ msg)
{
    __shared__ __align__(16) char smem_all[29696];
    bf16* hp = (bf16*)smem_all;                   // [64][232]; wave w owns rows
                                                  // [16w,16w+16), reused x4 tiles

    const int tid = threadIdx.x, w = tid >> 6, lane = tid & 63;
    const int col = lane & 15, quad = lane >> 4, row0 = quad * 4;
    const int myrow = w * 16;
    const int blk = blockIdx.x * 256;             // 4 tiles x 64 edges

    // h pad cols [200,224) of OWN rows: col200=1 (bm2 slot), rest 0.
    // Written ONCE: tiles only overwrite cols [0,200).
    if (lane < 48) {
        int r = lane / 3, ch = lane - r * 3;
        bf16x8 z = {};
        if (ch == 0) z[0] = (bf16)1.f;
        *(bf16x8*)(hp + (myrow + r) * 232 + 200 + ch * 8) = z;
    }

    // ---- all 4 edata loads upfront (independent) ----
    const int eoff = myrow + col;
    int4 ed0 = edata[blk + 0 * 64 + eoff];
    int4 ed1 = edata[blk + 1 * 64 + eoff];
    int4 ed2 = edata[blk + 2 * 64 + eoff];
    int4 ed3 = edata[blk + 3 * 64 + eoff];

    // ---- rolling 2-deep pipeline: fa/fb alternate ----
    Frags fa, fb;
    load_frags(xc, ed0, quad, fa);
    load_frags(xc, ed1, quad, fb);

    compute_tile<COUT>(fa, ed0, hp, myrow, col, quad, row0, lane,
                       blk + 0 * 64 + myrow, Wm1B, SelB, Wm2B, W2B, msg);
    load_frags(xc, ed2, quad, fa);
    compute_tile<COUT>(fb, ed1, hp, myrow, col, quad, row0, lane,
                       blk + 1 * 64 + myrow, Wm1B, SelB, Wm2B, W2B, msg);
    load_frags(xc, ed3, quad, fb);
    compute_tile<COUT>(fa, ed2, hp, myrow, col, quad, row0, lane,
                       blk + 2 * 64 + myrow, Wm1B, SelB, Wm2B, W2B, msg);
    compute_tile<COUT>(fb, ed3, hp, myrow, col, quad, row0, lane,
                       blk + 3 * 64 + myrow, Wm1B, SelB, Wm2B, W2B, msg);
}

// ===========================================================================
// Fused aggregation + next node term. 16 lanes per node; width-16 shuffles;
// fma order identical to the original node_kernel -> numerically identical.
// Writes the merged xc row: hi (bf16 x) at cols [0,32), lo residual at [32,64).
// ===========================================================================
template<int CNEXT>
__global__ __launch_bounds__(256) void agg_fused(
    const bf16* __restrict__ msg, const int* __restrict__ offsets,
    const float* __restrict__ bufc,
    const float* __restrict__ W1n, const float* __restrict__ b1n,
    float* __restrict__ bufn,
    bf16* __restrict__ xc) {
    int gh = (blockIdx.x * 256 + threadIdx.x) >> 4;
    int lane = threadIdx.x & 15;
    int s0 = offsets[gh], s1 = offsets[gh + 1];
    float r0 = 0.f, r1 = 0.f;
    if (lane < 15) {
        float v0 = 0.f, v1 = 0.f;
        const unsigned int* mp =
            (const unsigned int*)(msg + (size_t)s0 * 32 + lane * 2);
        int cnt = s1 - s0, j = 0;
        for (; j + 4 <= cnt; j += 4) {
            unsigned int u0 = mp[(size_t)(j + 0) * 16];
            unsigned int u1 = mp[(size_t)(j + 1) * 16];
            unsigned int u2 = mp[(size_t)(j + 2) * 16];
            unsigned int u3 = mp[(size_t)(j + 3) * 16];
            union { unsigned int u; bf16 b[2]; } c0, c1, c2, c3;
            c0.u = u0; c1.u = u1; c2.u = u2; c3.u = u3;
            v0 += (float)c0.b[0]; v1 += (float)c0.b[1];
            v0 += (float)c1.b[0]; v1 += (float)c1.b[1];
            v0 += (float)c2.b[0]; v1 += (float)c2.b[1];
            v0 += (float)c3.b[0]; v1 += (float)c3.b[1];
        }
        for (; j < cnt; ++j) {
            union { unsigned int u; bf16 b[2]; } cv;
            cv.u = mp[(size_t)j * 16];
            v0 += (float)cv.b[0]; v1 += (float)cv.b[1];
        }
        float f0 = bufc[(size_t)gh * 30 + 2 * lane] + v0;
        float f1 = bufc[(size_t)gh * 30 + 2 * lane + 1] + v1;
        r0 = fmaxf(f0, 0.f);
        r1 = fmaxf(f1, 0.f);
        bf16 h0 = (bf16)r0, h1 = (bf16)r1;
        union { bf16 h[2]; unsigned int u; } hi;
        hi.h[0] = h0; hi.h[1] = h1;
        *(unsigned int*)(xc + (size_t)gh * 64 + 2 * lane) = hi.u;
        *(unsigned int*)(xc + (size_t)gh * 64 + 32 + 2 * lane) =
            pk_bf16(r0 - (float)h0, r1 - (float)h1);
    } else {
        *(unsigned int*)(xc + (size_t)gh * 64 + 30) = pk_bf16(1.f, 0.f);
        *(unsigned int*)(xc + (size_t)gh * 64 + 62) = 0u;
    }
    // ---- next node term (fma order == original node_kernel) ----
    if (CNEXT == 30) {
        float acc0 = 0.f, acc1 = 0.f;
        if (lane < 15) { acc0 = b1n[2 * lane]; acc1 = b1n[2 * lane + 1]; }
        for (int k2 = 0; k2 < 15; ++k2) {
            float rk0 = __shfl(r0, k2, 16);
            float rk1 = __shfl(r1, k2, 16);
            if (lane < 15) {
                const float* w0 = W1n + (2 * k2) * 30 + 2 * lane;
                const float* w1 = W1n + (2 * k2 + 1) * 30 + 2 * lane;
                acc0 = fmaf(rk0, w0[0], acc0);
                acc1 = fmaf(rk0, w0[1], acc1);
                acc0 = fmaf(rk1, w1[0], acc0);
                acc1 = fmaf(rk1, w1[1], acc1);
            }
        }
        if (lane < 15) {
            bufn[(size_t)gh * 30 + 2 * lane] = acc0;
            bufn[(size_t)gh * 30 + 2 * lane + 1] = acc1;
        }
    } else {
        float acc = b1n[0];
        for (int k2 = 0; k2 < 15; ++k2) {
            float rk0 = __shfl(r0, k2, 16);
            float rk1 = __shfl(r1, k2, 16);
            acc = fmaf(rk0, W1n[2 * k2], acc);
            acc = fmaf(rk1, W1n[2 * k2 + 1], acc);
        }
        if (lane == 0) bufn[gh] = acc;
    }
}

// Final aggregation, compact msg1[e]: out[gh] += sum (same lane->j order)
__global__ __launch_bounds__(256) void agg_last(const bf16* __restrict__ msg1,
                                                const int* __restrict__ offsets,
                                                float* __restrict__ out) {
    int gh = (blockIdx.x * 256 + threadIdx.x) >> 5;
    int lane = threadIdx.x & 31;
    int s0 = offsets[gh], s1 = offsets[gh + 1];
    float v = 0.f;
    for (int j = s0 + lane; j < s1; j += 32) v += (float)msg1[j];
#pragma unroll
    for (int o = 16; o > 0; o >>= 1) v += __shfl_xor(v, o);
    if (lane == 0) out[gh] += v;
}

// ===========================================================================
extern "C" void kernel_launch(void* const* d_in, const int* in_sizes, int n_in,
                              void* d_out, int out_size, void* d_ws, size_t ws_size,
                              hipStream_t stream) {
    const float* features = (const float*)d_in[0];
    const int*   edges    = (const int*)d_in[1];
    const float* ew       = (const float*)d_in[2];

    const float* W1_d  = (const float*)d_in[3];
    const float* b1_d  = (const float*)d_in[4];
    const float* Wm1_d = (const float*)d_in[5];
    const float* bm1_d = (const float*)d_in[6];
    const float* Wm2_d = (const float*)d_in[7];
    const float* bm2_d = (const float*)d_in[8];
    const float* W2_d  = (const float*)d_in[9];
    const float* b2_d  = (const float*)d_in[10];

    const float* W1_h  = (const float*)d_in[11];
    const float* b1_h  = (const float*)d_in[12];
    const float* Wm1_h = (const float*)d_in[13];
    const float* bm1_h = (const float*)d_in[14];
    const float* Wm2_h = (const float*)d_in[15];
    const float* bm2_h = (const float*)d_in[16];
    const float* W2_h  = (const float*)d_in[17];
    const float* b2_h  = (const float*)d_in[18];

    const float* W1_o  = (const float*)d_in[19];
    const float* b1_o  = (const float*)d_in[20];
    const float* Wm1_o = (const float*)d_in[21];
    const float* bm1_o = (const float*)d_in[22];
    const float* Wm2_o = (const float*)d_in[23];
    const float* bm2_o = (const float*)d_in[24];
    const float* W2_o  = (const float*)d_in[25];
    const float* b2_o  = (const float*)d_in[26];

    const int* src = edges;
    const int* dst = edges + N_EDGES;
    float* out = (float*)d_out;

    // ---- workspace carve-up ----
    char* p = (char*)d_ws;
    auto alloc = [&](size_t bytes) { char* r = p; p += (bytes + 63) & ~(size_t)63; return r; };
    float* bufA    = (float*)alloc((size_t)N_NODES * 30 * 4);
    float* bufB    = (float*)alloc((size_t)N_NODES * 30 * 4);
    bf16*  msg     = (bf16*) alloc((size_t)N_EDGES * 32 * 2);
    bf16*  xc      = (bf16*) alloc((size_t)N_NODES * 64 * 2);
    int*   counts  = (int*)  alloc((size_t)N_NODES * 4);
    int*   offsets = (int*)  alloc((size_t)(N_NODES + 1) * 4);
    int*   cursor  = (int*)  alloc((size_t)N_NODES * 4);
    int4*  edata   = (int4*) alloc((size_t)N_EDGES * 16);
    float* Wm1T_d  = (float*)alloc((size_t)C_MSG * 4 * 4);
    bf16*  Wm1B_h  = (bf16*) alloc((size_t)26 * 512 * 2);
    bf16*  Wm1B_o  = (bf16*) alloc((size_t)26 * 512 * 2);
    bf16*  Wm2B_h  = (bf16*) alloc((size_t)14 * 512 * 2);
    bf16*  Wm2B_o  = (bf16*) alloc((size_t)14 * 512 * 2);
    bf16*  W2B_h   = (bf16*) alloc((size_t)2 * 512 * 2);
    bf16*  W2B_o   = (bf16*) alloc((size_t)1 * 512 * 2);
    bf16*  SelB    = (bf16*) alloc((size_t)8 * 512 * 2);

    // ---- setup ----
    hipMemsetAsync(counts, 0, (size_t)N_NODES * 4, stream);
    setup_a<<<3507, 256, 0, stream>>>(dst, counts,
        Wm1_h, bm1_h, Wm1_o, bm1_o, Wm2_h, bm2_h, Wm2_o, bm2_o,
        W2_h, b2_h, W2_o, b2_o, Wm1_d,
        Wm1B_h, Wm1B_o, Wm2B_h, Wm2B_o, W2B_h, W2B_o, SelB, Wm1T_d,
        features, W1_d, b1_d, bufA);
    scan_kernel<<<(N_NODES + 255) / 256, 256, 0, stream>>>(counts, offsets, cursor);
    scatter_kernel<<<N_EDGES / 256, 256, 0, stream>>>(src, dst, ew, cursor, edata);

    dim3 tb(256);
    dim3 eb_mfma(N_EDGES / 256);   // 4 tiles of 64 edges per block
    dim3 eb_valu(N_EDGES / 256);
    dim3 ab16(N_NODES * 16 / 256);
    dim3 ab32(N_NODES * 32 / 256);

    // ---- layer d ----
    edge_d_kernel<<<eb_valu, tb, 0, stream>>>(features, edata, ew,
        Wm1T_d, bm1_d, Wm2_d, bm2_d, W2_d, b2_d, msg);
    agg_fused<30><<<ab16, tb, 0, stream>>>(msg, offsets, bufA, W1_h, b1_h, bufB, xc);

    // ---- h1 ----
    edge_mfma<30><<<eb_mfma, tb, 0, stream>>>(xc, edata,
        Wm1B_h, SelB, Wm2B_h, W2B_h, msg);
    agg_fused<30><<<ab16, tb, 0, stream>>>(msg, offsets, bufB, W1_h, b1_h, bufA, xc);

    // ---- h2 ----
    edge_mfma<30><<<eb_mfma, tb, 0, stream>>>(xc, edata,
        Wm1B_h, SelB, Wm2B_h, W2B_h, msg);
    agg_fused<30><<<ab16, tb, 0, stream>>>(msg, offsets, bufA, W1_h, b1_h, bufB, xc);

    // ---- h3 (next node term = output layer -> writes d_out) ----
    edge_mfma<30><<<eb_mfma, tb, 0, stream>>>(xc, edata,
        Wm1B_h, SelB, Wm2B_h, W2B_h, msg);
    agg_fused<1><<<ab16, tb, 0, stream>>>(msg, offsets, bufB, W1_o, b1_o, out, xc);

    // ---- output layer (compact msg1) ----
    edge_mfma<1><<<eb_mfma, tb, 0, stream>>>(xc, edata,
        Wm1B_o, SelB, Wm2B_o, W2B_o, msg);
    agg_last<<<ab32, tb, 0, stream>>>(msg, offsets, out);
}

// Round 3
// 747.048 us; speedup vs baseline: 2.1772x; 2.1772x over previous
//
#include <hip/hip_runtime.h>

#define N_NODES 50000
#define N_EDGES 800000
#define C_MSG 200

typedef __bf16 bf16;
typedef __attribute__((ext_vector_type(8))) __bf16 bf16x8;
typedef __attribute__((ext_vector_type(4))) float f32x4;

static __device__ __forceinline__ unsigned int pk_bf16(float a, float b) {
    union { bf16 h[2]; unsigned int u; } cv;
    cv.h[0] = (bf16)a; cv.h[1] = (bf16)b;
    return cv.u;
}

static __device__ __forceinline__ f32x4 MF(bf16x8 a, bf16x8 b, f32x4 c) {
    return __builtin_amdgcn_mfma_f32_16x16x32_bf16(a, b, c, 0, 0, 0);
}

// ===========================================================================
// Weight packers (device fns) -> MFMA B-frag order (16x16x32), biases folded.
// Fragment f at out[f*512 + lane*8 + i]; lane holds B[k][n], k=kt*32+(lane>>4)*8+i.
// Paired N-tiles: pair p covers cols p*32 + 2*(lane&15) + parity.
// ===========================================================================
static __device__ void dev_pack_wm1(int tid, const float* W, const float* bm1,
                                    bf16* out) {
    int i = tid & 7, lane = (tid >> 3) & 63, rest = tid >> 9;
    int kt = rest % 2, t = rest / 2;
    int k = kt * 32 + ((lane >> 4) * 8) + i;
    int c = lane & 15;
    int n = (t < 12) ? ((t >> 1) * 32 + 2 * c + (t & 1)) : (192 + c);
    float v = 0.f;
    if (n < C_MSG) {
        if (k < 30)       v = W[k * C_MSG + n];
        else if (k == 30) v = bm1[n];
        else if (k >= 32) v = W[(k - 2) * C_MSG + n];
    }
    out[tid] = (bf16)v;
}

static __device__ void dev_pack_wm2(int tid, const float* W, const float* bm2,
                                    bf16* out) {
    int i = tid & 7, lane = (tid >> 3) & 63, rest = tid >> 9;
    int kt = rest % 7, nt = rest / 7;
    int k = kt * 32 + ((lane >> 4) * 8) + i;
    int n = 2 * (lane & 15) + nt;
    float v = 0.f;
    if (n < 30) {
        if (k < C_MSG)       v = W[k * 30 + n];
        else if (k == C_MSG) v = bm2[n];
    }
    out[tid] = (bf16)v;
}

static __device__ void dev_pack_w2h(int tid, const float* W, const float* b2,
                                    bf16* out) {
    int i = tid & 7, lane = (tid >> 3) & 63, nt = tid >> 9;
    int k = ((lane >> 4) * 8) + i;
    int n = 2 * (lane & 15) + nt;
    float v = 0.f;
    if (n < 30) {
        if (k < 30)       v = W[k * 30 + n];
        else if (k == 30) v = b2[n];
    }
    out[tid] = (bf16)v;
}

static __device__ void dev_pack_w2o(int tid, const float* W, const float* b2,
                                    bf16* out) {
    int i = tid & 7, lane = (tid >> 3) & 63;
    int k = ((lane >> 4) * 8) + i;
    int n = lane & 15;
    float v = 0.f;
    if (n == 0) {
        if (k < 30)       v = W[k];
        else if (k == 30) v = b2[0];
    }
    out[tid] = (bf16)v;
}

static __device__ void dev_pack_sel(int tid, bf16* out) {
    int i = tid & 7, lane = (tid >> 3) & 63, f = tid >> 9;
    int kt = f >> 1, nt = f & 1;
    int kloc = ((lane >> 4) * 8) + i;
    int n = 2 * (lane & 15) + nt;
    float v = (kloc == n && n < 30) ? ((kt & 1) ? -1.f : 1.f) : 0.f;
    out[tid] = (bf16)v;
}

// ===========================================================================
// setup_a: count (3125 blocks) + pack_all (186) + node_d (196) in ONE dispatch
// ===========================================================================
__global__ __launch_bounds__(256) void setup_a(
    const int* __restrict__ dst, int* __restrict__ counts,
    const float* __restrict__ Wm1_h, const float* __restrict__ bm1_h,
    const float* __restrict__ Wm1_o, const float* __restrict__ bm1_o,
    const float* __restrict__ Wm2_h, const float* __restrict__ bm2_h,
    const float* __restrict__ Wm2_o, const float* __restrict__ bm2_o,
    const float* __restrict__ W2_h,  const float* __restrict__ b2_h,
    const float* __restrict__ W2_o,  const float* __restrict__ b2_o,
    const float* __restrict__ Wm1_d,
    bf16* __restrict__ Wm1B_h, bf16* __restrict__ Wm1B_o,
    bf16* __restrict__ Wm2B_h, bf16* __restrict__ Wm2B_o,
    bf16* __restrict__ W2B_h,  bf16* __restrict__ W2B_o,
    bf16* __restrict__ SelB,   float* __restrict__ Wm1T_d,
    const float* __restrict__ features, const float* __restrict__ W1_d,
    const float* __restrict__ b1_d, float* __restrict__ bufA) {
    int b = blockIdx.x, t = threadIdx.x;
    if (b < 3125) {                                  // count
        int e = b * 256 + t;
        if (e < N_EDGES) atomicAdd(&counts[dst[e]], 1);
    } else if (b < 3311) {                           // pack_all
        int pb = b - 3125;
        if (pb < 52)       dev_pack_wm1(pb * 256 + t, Wm1_h, bm1_h, Wm1B_h);
        else if (pb < 104) dev_pack_wm1((pb - 52) * 256 + t, Wm1_o, bm1_o, Wm1B_o);
        else if (pb < 132) dev_pack_wm2((pb - 104) * 256 + t, Wm2_h, bm2_h, Wm2B_h);
        else if (pb < 160) dev_pack_wm2((pb - 132) * 256 + t, Wm2_o, bm2_o, Wm2B_o);
        else if (pb < 164) dev_pack_w2h((pb - 160) * 256 + t, W2_h, b2_h, W2B_h);
        else if (pb < 166) dev_pack_w2o((pb - 164) * 256 + t, W2_o, b2_o, W2B_o);
        else if (pb < 182) dev_pack_sel((pb - 166) * 256 + t, SelB);
        else {
            int i = (pb - 182) * 256 + t;
            if (i < C_MSG * 4) Wm1T_d[i] = Wm1_d[(i & 3) * C_MSG + (i >> 2)];
        }
    } else {                                         // node term, layer d
        int n = (b - 3311) * 256 + t;
        if (n < N_NODES) {
            float xv = features[n];
            for (int o = 0; o < 30; ++o)
                bufA[n * 30 + o] = fmaf(xv, W1_d[o], b1_d[o]);
        }
    }
}

// Parallel scan over counts
__global__ __launch_bounds__(256) void scan_kernel(const int* __restrict__ counts,
                                                   int* __restrict__ offsets,
                                                   int* __restrict__ cursor) {
    __shared__ int ws[4];
    const int b = blockIdx.x, t = threadIdx.x;
    const int lane = t & 63, wv = t >> 6;
    int acc = 0;
    for (int i = t; i < b * 256; i += 256) acc += counts[i];
#pragma unroll
    for (int d = 32; d > 0; d >>= 1) acc += __shfl_xor(acc, d);
    if (lane == 0) ws[wv] = acc;
    __syncthreads();
    int base = ws[0] + ws[1] + ws[2] + ws[3];
    __syncthreads();
    int i = b * 256 + t;
    int v = (i < N_NODES) ? counts[i] : 0;
    int inc = v;
#pragma unroll
    for (int d = 1; d < 64; d <<= 1) {
        int u = __shfl_up(inc, d);
        if (lane >= d) inc += u;
    }
    if (lane == 63) ws[wv] = inc;
    __syncthreads();
    int waveoff = 0;
    for (int k = 0; k < wv; ++k) waveoff += ws[k];
    int excl = base + waveoff + inc - v;
    if (i < N_NODES) { offsets[i] = excl; cursor[i] = excl; }
    if (i == N_NODES - 1) offsets[N_NODES] = excl + v;
}

// scatter: ONE int4 stream {src, dst, ewbf, perm} in perm order
__global__ __launch_bounds__(256) void scatter_kernel(
    const int* __restrict__ src, const int* __restrict__ dst,
    const float* __restrict__ ew, int* __restrict__ cursor,
    int4* __restrict__ edata) {
    int e = blockIdx.x * 256 + threadIdx.x;
    if (e < N_EDGES) {
        int d = dst[e];
        int p = atomicAdd(&cursor[d], 1);
        edata[p] = make_int4(src[e], d, (int)pk_bf16(ew[2 * e], ew[2 * e + 1]), e);
    }
}

// ===========================================================================
// Layer-d edge kernel (CIN=1): full-fp32 VALU path, perm order
// ===========================================================================
__global__ __launch_bounds__(256) void edge_d_kernel(
    const float* __restrict__ x, const int4* __restrict__ edata,
    const float* __restrict__ ew,
    const float* __restrict__ Wm1T, const float* __restrict__ bm1,
    const float* __restrict__ Wm2, const float* __restrict__ bm2,
    const float* __restrict__ W2, const float* __restrict__ b2, bf16* __restrict__ msg)
{
    int t = blockIdx.x * 256 + threadIdx.x;
    int4 ed = edata[t];
    float xi = x[ed.y], xj = x[ed.x];
    int p = ed.w;
    float e0 = ew[2 * p], e1 = ew[2 * p + 1];
    float m = bm2[0];
    for (int j = 0; j < C_MSG; ++j) {
        const float* __restrict__ wr = Wm1T + j * 4;
        float h = bm1[j];
        h = fmaf(xi, wr[0], h);
        h = fmaf(xj, wr[1], h);
        h = fmaf(e0, wr[2], h);
        h = fmaf(e1, wr[3], h);
        h = fmaxf(h, 0.f);
        m = fmaf(h, Wm2[j], m);
    }
    float md = m * (xi - xj);
    for (int o = 0; o < 15; ++o) {
        float f0 = fmaf(md, W2[2 * o], b2[2 * o]);
        float f1 = fmaf(md, W2[2 * o + 1], b2[2 * o + 1]);
        *(unsigned int*)(msg + (size_t)t * 32 + 2 * o) = pk_bf16(f0, f1);
    }
}

// ===========================================================================
// MFMA edge kernel v11: v10's pipeline (validated correct) with spill-proof
// codegen.
//  R2 post-mortem: v10's WRITE_SIZE 50MB->915MB + FETCH 66->513MB = SCRATCH
//  traffic: compute_tile(const Frags&) was not inlined / frags forced to
//  stack; ~800K threads x ~500B stack round-trip matches the delta. The
//  pipeline STRUCTURE passed (same absmax) — only codegen broke.
//  v11: identical algorithm, but
//   (1) tile compute + frag loads are PREPROCESSOR MACROS (textual inline,
//       cannot be skipped); MFMA via tiny MF() wrapper; no struct, no
//       reference, no address-taken values -> nothing can go to scratch.
//   (2) __launch_bounds__(256,2): VGPR cap 256 so ~120-140 live regs never
//       spill. Occupancy drops; ILP pipeline replaces TLP (R1 theory).
//   (3) merged xc[node][64] row retained (one fully-used 128B line per
//       random endpoint gather).
//  Verification signal: WRITE_SIZE must return to ~50MB.
// ===========================================================================

#define LOAD_FRAGS(P, ED) do {                                                \
    const bf16* rd_ = xc + (size_t)(ED).y * 64 + quad * 8;                    \
    const bf16* rs_ = xc + (size_t)(ED).x * 64 + quad * 8;                    \
    P##A0 = *(const bf16x8*)(rd_);                                            \
    P##a2 = *(const bf16x8*)(rd_ + 32);                                       \
    P##A1 = *(const bf16x8*)(rs_);                                            \
    P##a3 = *(const bf16x8*)(rs_ + 32);                                       \
} while (0)

// Per-tile compute: identical op sequence to v9/v10 (bit-identical output).
// Uses in-scope: hp, myrow, col, quad, row0, lane, Wm1B, SelB, Wm2B, W2B,
// msg, COUT. ew patch (rows 30/31 of src slot) applied at consume time;
// selector rows 30/31 are zero so the patch never reaches the diff.
#define COMPUTE_TILE(P, EDZ, EBASE) do {                                      \
    if (quad == 3) {                                                          \
        union { unsigned int u; bf16 b[2]; } cv_;                             \
        cv_.u = (unsigned int)(EDZ);                                          \
        P##A1[6] = cv_.b[0];                                                  \
        P##A1[7] = cv_.b[1];                                                  \
    }                                                                         \
    /* diff[16x32] via selector GEMM */                                       \
    f32x4 dc0_ = {0.f,0.f,0.f,0.f}, dc1_ = {0.f,0.f,0.f,0.f};                 \
    dc0_ = MF(P##A0, *(const bf16x8*)(SelB + (size_t)0*512 + lane*8), dc0_);  \
    dc1_ = MF(P##A0, *(const bf16x8*)(SelB + (size_t)1*512 + lane*8), dc1_);  \
    dc0_ = MF(P##A1, *(const bf16x8*)(SelB + (size_t)2*512 + lane*8), dc0_);  \
    dc1_ = MF(P##A1, *(const bf16x8*)(SelB + (size_t)3*512 + lane*8), dc1_);  \
    dc0_ = MF(P##a2, *(const bf16x8*)(SelB + (size_t)4*512 + lane*8), dc0_);  \
    dc1_ = MF(P##a2, *(const bf16x8*)(SelB + (size_t)5*512 + lane*8), dc1_);  \
    dc0_ = MF(P##a3, *(const bf16x8*)(SelB + (size_t)6*512 + lane*8), dc0_);  \
    dc1_ = MF(P##a3, *(const bf16x8*)(SelB + (size_t)7*512 + lane*8), dc1_);  \
    /* GEMM1: own 16 edges, all 6 N-pairs */                                  \
    _Pragma("unroll")                                                         \
    for (int p_ = 0; p_ < 6; ++p_) {                                          \
        const bf16* Wf_ = Wm1B + (size_t)(4*p_)*512 + lane*8;                 \
        bf16x8 be0_ = *(const bf16x8*)(Wf_);                                  \
        bf16x8 be1_ = *(const bf16x8*)(Wf_ + 512);                            \
        bf16x8 bo0_ = *(const bf16x8*)(Wf_ + 1024);                           \
        bf16x8 bo1_ = *(const bf16x8*)(Wf_ + 1536);                           \
        f32x4 ae_ = {0.f,0.f,0.f,0.f}, ao_ = {0.f,0.f,0.f,0.f};               \
        ae_ = MF(P##A0, be0_, ae_);                                           \
        ae_ = MF(P##A1, be1_, ae_);                                           \
        ao_ = MF(P##A0, bo0_, ao_);                                           \
        ao_ = MF(P##A1, bo1_, ao_);                                           \
        _Pragma("unroll")                                                     \
        for (int rg_ = 0; rg_ < 4; ++rg_) {                                   \
            unsigned int u_ = pk_bf16(fmaxf(ae_[rg_],0.f), fmaxf(ao_[rg_],0.f)); \
            *(unsigned int*)(hp + (myrow + row0 + rg_)*232 + p_*32 + 2*col) = u_; \
        }                                                                     \
    }                                                                         \
    {   /* leftover N-tile 12: cols 192..199 real */                          \
        const bf16* Wf_ = Wm1B + (size_t)24*512 + lane*8;                     \
        bf16x8 b0_ = *(const bf16x8*)(Wf_);                                   \
        bf16x8 b1_ = *(const bf16x8*)(Wf_ + 512);                             \
        f32x4 acc_ = {0.f,0.f,0.f,0.f};                                       \
        acc_ = MF(P##A0, b0_, acc_);                                          \
        acc_ = MF(P##A1, b1_, acc_);                                          \
        if (col < 8) {                                                        \
            _Pragma("unroll")                                                 \
            for (int rg_ = 0; rg_ < 4; ++rg_)                                 \
                hp[(myrow + row0 + rg_)*232 + 192 + col] =                    \
                    (bf16)fmaxf(acc_[rg_], 0.f);                              \
        }                                                                     \
    }                                                                         \
    /* NO __syncthreads: rows [myrow,myrow+16) wave-private */                \
    /* GEMM2: h[16x224] @ Wm2[224x32]; md = m*diff */                         \
    f32x4 m0_ = {0.f,0.f,0.f,0.f}, m1_ = {0.f,0.f,0.f,0.f};                   \
    _Pragma("unroll")                                                         \
    for (int kt_ = 0; kt_ < 7; ++kt_) {                                       \
        bf16x8 a_ = *(const bf16x8*)(hp + (myrow + col)*232 + kt_*32 + quad*8); \
        m0_ = MF(a_, *(const bf16x8*)(Wm2B + (size_t)kt_*512 + lane*8), m0_); \
        m1_ = MF(a_, *(const bf16x8*)(Wm2B + (size_t)(7+kt_)*512 + lane*8), m1_); \
    }                                                                         \
    /* md overwrites OWN h rows, cols 0-31 (dead after own GEMM2) */          \
    _Pragma("unroll")                                                         \
    for (int rg_ = 0; rg_ < 4; ++rg_) {                                       \
        unsigned int u_ = (col == 15) ? pk_bf16(1.f, 0.f)                     \
                        : pk_bf16(m0_[rg_]*dc0_[rg_], m1_[rg_]*dc1_[rg_]);    \
        *(unsigned int*)(hp + (myrow + row0 + rg_)*232 + 2*col) = u_;         \
    }                                                                         \
    /* GEMM3: md[16x32] @ W2[32xN] -> msg */                                  \
    bf16x8 am_ = *(const bf16x8*)(hp + (myrow + col)*232 + quad*8);           \
    if (COUT == 30) {                                                         \
        f32x4 c0_ = {0.f,0.f,0.f,0.f}, c1_ = {0.f,0.f,0.f,0.f};               \
        c0_ = MF(am_, *(const bf16x8*)(W2B + lane*8), c0_);                   \
        c1_ = MF(am_, *(const bf16x8*)(W2B + 512 + lane*8), c1_);             \
        _Pragma("unroll")                                                     \
        for (int rg_ = 0; rg_ < 4; ++rg_)                                     \
            *(unsigned int*)(msg + (size_t)((EBASE) + row0 + rg_)*32 + 2*col) = \
                pk_bf16(c0_[rg_], c1_[rg_]);                                  \
    } else {                                                                  \
        /* COUT=1: compact msg1[e] — one 8B store per col==0 lane */          \
        f32x4 c0_ = {0.f,0.f,0.f,0.f};                                        \
        c0_ = MF(am_, *(const bf16x8*)(W2B + lane*8), c0_);                   \
        if (col == 0) {                                                       \
            union { bf16 h[4]; unsigned long long u; } pk4_;                  \
            _Pragma("unroll")                                                 \
            for (int rg_ = 0; rg_ < 4; ++rg_) pk4_.h[rg_] = (bf16)c0_[rg_];   \
            *(unsigned long long*)(msg + ((EBASE) + row0)) = pk4_.u;          \
        }                                                                     \
    }                                                                         \
} while (0)

template<int COUT>
__global__ __launch_bounds__(256, 2) void edge_mfma(
    const bf16* __restrict__ xc, const int4* __restrict__ edata,
    const bf16* __restrict__ Wm1B, const bf16* __restrict__ SelB,
    const bf16* __restrict__ Wm2B, const bf16* __restrict__ W2B,
    bf16* __restrict__ msg)
{
    __shared__ __align__(16) char smem_all[29696];
    bf16* hp = (bf16*)smem_all;                   // [64][232]; wave w owns rows
                                                  // [16w,16w+16), reused x4 tiles

    const int tid = threadIdx.x, w = tid >> 6, lane = tid & 63;
    const int col = lane & 15, quad = lane >> 4, row0 = quad * 4;
    const int myrow = w * 16;
    const int blk = blockIdx.x * 256;             // 4 tiles x 64 edges

    // h pad cols [200,224) of OWN rows: col200=1 (bm2 slot), rest 0.
    // Written ONCE: tiles only overwrite cols [0,200).
    if (lane < 48) {
        int r = lane / 3, ch = lane - r * 3;
        bf16x8 z = {};
        if (ch == 0) z[0] = (bf16)1.f;
        *(bf16x8*)(hp + (myrow + r) * 232 + 200 + ch * 8) = z;
    }

    // ---- all 4 edata loads upfront (independent) ----
    const int eoff = myrow + col;
    int4 ed0 = edata[blk + 0 * 64 + eoff];
    int4 ed1 = edata[blk + 1 * 64 + eoff];
    int4 ed2 = edata[blk + 2 * 64 + eoff];
    int4 ed3 = edata[blk + 3 * 64 + eoff];

    // ---- rolling 2-deep pipeline over 4 tiles ----
    bf16x8 pA0, pA1, pa2, pa3, qA0, qA1, qa2, qa3;
    LOAD_FRAGS(p, ed0);
    LOAD_FRAGS(q, ed1);

    COMPUTE_TILE(p, ed0.z, blk + 0 * 64 + myrow);
    LOAD_FRAGS(p, ed2);
    COMPUTE_TILE(q, ed1.z, blk + 1 * 64 + myrow);
    LOAD_FRAGS(q, ed3);
    COMPUTE_TILE(p, ed2.z, blk + 2 * 64 + myrow);
    COMPUTE_TILE(q, ed3.z, blk + 3 * 64 + myrow);
}

// ===========================================================================
// Fused aggregation + next node term. 16 lanes per node; width-16 shuffles;
// fma order identical to the original node_kernel -> numerically identical.
// Writes the merged xc row: hi (bf16 x) at cols [0,32), lo residual at [32,64).
// ===========================================================================
template<int CNEXT>
__global__ __launch_bounds__(256) void agg_fused(
    const bf16* __restrict__ msg, const int* __restrict__ offsets,
    const float* __restrict__ bufc,
    const float* __restrict__ W1n, const float* __restrict__ b1n,
    float* __restrict__ bufn,
    bf16* __restrict__ xc) {
    int gh = (blockIdx.x * 256 + threadIdx.x) >> 4;
    int lane = threadIdx.x & 15;
    int s0 = offsets[gh], s1 = offsets[gh + 1];
    float r0 = 0.f, r1 = 0.f;
    if (lane < 15) {
        float v0 = 0.f, v1 = 0.f;
        const unsigned int* mp =
            (const unsigned int*)(msg + (size_t)s0 * 32 + lane * 2);
        int cnt = s1 - s0, j = 0;
        for (; j + 4 <= cnt; j += 4) {
            unsigned int u0 = mp[(size_t)(j + 0) * 16];
            unsigned int u1 = mp[(size_t)(j + 1) * 16];
            unsigned int u2 = mp[(size_t)(j + 2) * 16];
            unsigned int u3 = mp[(size_t)(j + 3) * 16];
            union { unsigned int u; bf16 b[2]; } c0, c1, c2, c3;
            c0.u = u0; c1.u = u1; c2.u = u2; c3.u = u3;
            v0 += (float)c0.b[0]; v1 += (float)c0.b[1];
            v0 += (float)c1.b[0]; v1 += (float)c1.b[1];
            v0 += (float)c2.b[0]; v1 += (float)c2.b[1];
            v0 += (float)c3.b[0]; v1 += (float)c3.b[1];
        }
        for (; j < cnt; ++j) {
            union { unsigned int u; bf16 b[2]; } cv;
            cv.u = mp[(size_t)j * 16];
            v0 += (float)cv.b[0]; v1 += (float)cv.b[1];
        }
        float f0 = bufc[(size_t)gh * 30 + 2 * lane] + v0;
        float f1 = bufc[(size_t)gh * 30 + 2 * lane + 1] + v1;
        r0 = fmaxf(f0, 0.f);
        r1 = fmaxf(f1, 0.f);
        bf16 h0 = (bf16)r0, h1 = (bf16)r1;
        union { bf16 h[2]; unsigned int u; } hi;
        hi.h[0] = h0; hi.h[1] = h1;
        *(unsigned int*)(xc + (size_t)gh * 64 + 2 * lane) = hi.u;
        *(unsigned int*)(xc + (size_t)gh * 64 + 32 + 2 * lane) =
            pk_bf16(r0 - (float)h0, r1 - (float)h1);
    } else {
        *(unsigned int*)(xc + (size_t)gh * 64 + 30) = pk_bf16(1.f, 0.f);
        *(unsigned int*)(xc + (size_t)gh * 64 + 62) = 0u;
    }
    // ---- next node term (fma order == original node_kernel) ----
    if (CNEXT == 30) {
        float acc0 = 0.f, acc1 = 0.f;
        if (lane < 15) { acc0 = b1n[2 * lane]; acc1 = b1n[2 * lane + 1]; }
        for (int k2 = 0; k2 < 15; ++k2) {
            float rk0 = __shfl(r0, k2, 16);
            float rk1 = __shfl(r1, k2, 16);
            if (lane < 15) {
                const float* w0 = W1n + (2 * k2) * 30 + 2 * lane;
                const float* w1 = W1n + (2 * k2 + 1) * 30 + 2 * lane;
                acc0 = fmaf(rk0, w0[0], acc0);
                acc1 = fmaf(rk0, w0[1], acc1);
                acc0 = fmaf(rk1, w1[0], acc0);
                acc1 = fmaf(rk1, w1[1], acc1);
            }
        }
        if (lane < 15) {
            bufn[(size_t)gh * 30 + 2 * lane] = acc0;
            bufn[(size_t)gh * 30 + 2 * lane + 1] = acc1;
        }
    } else {
        float acc = b1n[0];
        for (int k2 = 0; k2 < 15; ++k2) {
            float rk0 = __shfl(r0, k2, 16);
            float rk1 = __shfl(r1, k2, 16);
            acc = fmaf(rk0, W1n[2 * k2], acc);
            acc = fmaf(rk1, W1n[2 * k2 + 1], acc);
        }
        if (lane == 0) bufn[gh] = acc;
    }
}

// Final aggregation, compact msg1[e]: out[gh] += sum (same lane->j order)
__global__ __launch_bounds__(256) void agg_last(const bf16* __restrict__ msg1,
                                                const int* __restrict__ offsets,
                                                float* __restrict__ out) {
    int gh = (blockIdx.x * 256 + threadIdx.x) >> 5;
    int lane = threadIdx.x & 31;
    int s0 = offsets[gh], s1 = offsets[gh + 1];
    float v = 0.f;
    for (int j = s0 + lane; j < s1; j += 32) v += (float)msg1[j];
#pragma unroll
    for (int o = 16; o > 0; o >>= 1) v += __shfl_xor(v, o);
    if (lane == 0) out[gh] += v;
}

// ===========================================================================
extern "C" void kernel_launch(void* const* d_in, const int* in_sizes, int n_in,
                              void* d_out, int out_size, void* d_ws, size_t ws_size,
                              hipStream_t stream) {
    const float* features = (const float*)d_in[0];
    const int*   edges    = (const int*)d_in[1];
    const float* ew       = (const float*)d_in[2];

    const float* W1_d  = (const float*)d_in[3];
    const float* b1_d  = (const float*)d_in[4];
    const float* Wm1_d = (const float*)d_in[5];
    const float* bm1_d = (const float*)d_in[6];
    const float* Wm2_d = (const float*)d_in[7];
    const float* bm2_d = (const float*)d_in[8];
    const float* W2_d  = (const float*)d_in[9];
    const float* b2_d  = (const float*)d_in[10];

    const float* W1_h  = (const float*)d_in[11];
    const float* b1_h  = (const float*)d_in[12];
    const float* Wm1_h = (const float*)d_in[13];
    const float* bm1_h = (const float*)d_in[14];
    const float* Wm2_h = (const float*)d_in[15];
    const float* bm2_h = (const float*)d_in[16];
    const float* W2_h  = (const float*)d_in[17];
    const float* b2_h  = (const float*)d_in[18];

    const float* W1_o  = (const float*)d_in[19];
    const float* b1_o  = (const float*)d_in[20];
    const float* Wm1_o = (const float*)d_in[21];
    const float* bm1_o = (const float*)d_in[22];
    const float* Wm2_o = (const float*)d_in[23];
    const float* bm2_o = (const float*)d_in[24];
    const float* W2_o  = (const float*)d_in[25];
    const float* b2_o  = (const float*)d_in[26];

    const int* src = edges;
    const int* dst = edges + N_EDGES;
    float* out = (float*)d_out;

    // ---- workspace carve-up ----
    char* p = (char*)d_ws;
    auto alloc = [&](size_t bytes) { char* r = p; p += (bytes + 63) & ~(size_t)63; return r; };
    float* bufA    = (float*)alloc((size_t)N_NODES * 30 * 4);
    float* bufB    = (float*)alloc((size_t)N_NODES * 30 * 4);
    bf16*  msg     = (bf16*) alloc((size_t)N_EDGES * 32 * 2);
    bf16*  xc      = (bf16*) alloc((size_t)N_NODES * 64 * 2);
    int*   counts  = (int*)  alloc((size_t)N_NODES * 4);
    int*   offsets = (int*)  alloc((size_t)(N_NODES + 1) * 4);
    int*   cursor  = (int*)  alloc((size_t)N_NODES * 4);
    int4*  edata   = (int4*) alloc((size_t)N_EDGES * 16);
    float* Wm1T_d  = (float*)alloc((size_t)C_MSG * 4 * 4);
    bf16*  Wm1B_h  = (bf16*) alloc((size_t)26 * 512 * 2);
    bf16*  Wm1B_o  = (bf16*) alloc((size_t)26 * 512 * 2);
    bf16*  Wm2B_h  = (bf16*) alloc((size_t)14 * 512 * 2);
    bf16*  Wm2B_o  = (bf16*) alloc((size_t)14 * 512 * 2);
    bf16*  W2B_h   = (bf16*) alloc((size_t)2 * 512 * 2);
    bf16*  W2B_o   = (bf16*) alloc((size_t)1 * 512 * 2);
    bf16*  SelB    = (bf16*) alloc((size_t)8 * 512 * 2);

    // ---- setup ----
    hipMemsetAsync(counts, 0, (size_t)N_NODES * 4, stream);
    setup_a<<<3507, 256, 0, stream>>>(dst, counts,
        Wm1_h, bm1_h, Wm1_o, bm1_o, Wm2_h, bm2_h, Wm2_o, bm2_o,
        W2_h, b2_h, W2_o, b2_o, Wm1_d,
        Wm1B_h, Wm1B_o, Wm2B_h, Wm2B_o, W2B_h, W2B_o, SelB, Wm1T_d,
        features, W1_d, b1_d, bufA);
    scan_kernel<<<(N_NODES + 255) / 256, 256, 0, stream>>>(counts, offsets, cursor);
    scatter_kernel<<<N_EDGES / 256, 256, 0, stream>>>(src, dst, ew, cursor, edata);

    dim3 tb(256);
    dim3 eb_mfma(N_EDGES / 256);   // 4 tiles of 64 edges per block
    dim3 eb_valu(N_EDGES / 256);
    dim3 ab16(N_NODES * 16 / 256);
    dim3 ab32(N_NODES * 32 / 256);

    // ---- layer d ----
    edge_d_kernel<<<eb_valu, tb, 0, stream>>>(features, edata, ew,
        Wm1T_d, bm1_d, Wm2_d, bm2_d, W2_d, b2_d, msg);
    agg_fused<30><<<ab16, tb, 0, stream>>>(msg, offsets, bufA, W1_h, b1_h, bufB, xc);

    // ---- h1 ----
    edge_mfma<30><<<eb_mfma, tb, 0, stream>>>(xc, edata,
        Wm1B_h, SelB, Wm2B_h, W2B_h, msg);
    agg_fused<30><<<ab16, tb, 0, stream>>>(msg, offsets, bufB, W1_h, b1_h, bufA, xc);

    // ---- h2 ----
    edge_mfma<30><<<eb_mfma, tb, 0, stream>>>(xc, edata,
        Wm1B_h, SelB, Wm2B_h, W2B_h, msg);
    agg_fused<30><<<ab16, tb, 0, stream>>>(msg, offsets, bufA, W1_h, b1_h, bufB, xc);

    // ---- h3 (next node term = output layer -> writes d_out) ----
    edge_mfma<30><<<eb_mfma, tb, 0, stream>>>(xc, edata,
        Wm1B_h, SelB, Wm2B_h, W2B_h, msg);
    agg_fused<1><<<ab16, tb, 0, stream>>>(msg, offsets, bufB, W1_o, b1_o, out, xc);

    // ---- output layer (compact msg1) ----
    edge_mfma<1><<<eb_mfma, tb, 0, stream>>>(xc, edata,
        Wm1B_o, SelB, Wm2B_o, W2B_o, msg);
    agg_last<<<ab32, tb, 0, stream>>>(msg, offsets, out);
}

// Round 4
// 732.946 us; speedup vs baseline: 2.2191x; 1.0192x over previous
//
#include <hip/hip_runtime.h>

#define N_NODES 50000
#define N_EDGES 800000
#define C_MSG 200

typedef __bf16 bf16;
typedef __attribute__((ext_vector_type(8))) __bf16 bf16x8;
typedef __attribute__((ext_vector_type(4))) float f32x4;

static __device__ __forceinline__ unsigned int pk_bf16(float a, float b) {
    union { bf16 h[2]; unsigned int u; } cv;
    cv.h[0] = (bf16)a; cv.h[1] = (bf16)b;
    return cv.u;
}

static __device__ __forceinline__ f32x4 MF(bf16x8 a, bf16x8 b, f32x4 c) {
    return __builtin_amdgcn_mfma_f32_16x16x32_bf16(a, b, c, 0, 0, 0);
}

// ===========================================================================
// Weight packers (device fns) -> MFMA B-frag order (16x16x32), biases folded.
// Fragment f at out[f*512 + lane*8 + i]; lane holds B[k][n], k=kt*32+(lane>>4)*8+i.
// Paired N-tiles: pair p covers cols p*32 + 2*(lane&15) + parity.
// ===========================================================================
static __device__ void dev_pack_wm1(int tid, const float* W, const float* bm1,
                                    bf16* out) {
    int i = tid & 7, lane = (tid >> 3) & 63, rest = tid >> 9;
    int kt = rest % 2, t = rest / 2;
    int k = kt * 32 + ((lane >> 4) * 8) + i;
    int c = lane & 15;
    int n = (t < 12) ? ((t >> 1) * 32 + 2 * c + (t & 1)) : (192 + c);
    float v = 0.f;
    if (n < C_MSG) {
        if (k < 30)       v = W[k * C_MSG + n];
        else if (k == 30) v = bm1[n];
        else if (k >= 32) v = W[(k - 2) * C_MSG + n];
    }
    out[tid] = (bf16)v;
}

static __device__ void dev_pack_wm2(int tid, const float* W, const float* bm2,
                                    bf16* out) {
    int i = tid & 7, lane = (tid >> 3) & 63, rest = tid >> 9;
    int kt = rest % 7, nt = rest / 7;
    int k = kt * 32 + ((lane >> 4) * 8) + i;
    int n = 2 * (lane & 15) + nt;
    float v = 0.f;
    if (n < 30) {
        if (k < C_MSG)       v = W[k * 30 + n];
        else if (k == C_MSG) v = bm2[n];
    }
    out[tid] = (bf16)v;
}

static __device__ void dev_pack_w2h(int tid, const float* W, const float* b2,
                                    bf16* out) {
    int i = tid & 7, lane = (tid >> 3) & 63, nt = tid >> 9;
    int k = ((lane >> 4) * 8) + i;
    int n = 2 * (lane & 15) + nt;
    float v = 0.f;
    if (n < 30) {
        if (k < 30)       v = W[k * 30 + n];
        else if (k == 30) v = b2[n];
    }
    out[tid] = (bf16)v;
}

static __device__ void dev_pack_w2o(int tid, const float* W, const float* b2,
                                    bf16* out) {
    int i = tid & 7, lane = (tid >> 3) & 63;
    int k = ((lane >> 4) * 8) + i;
    int n = lane & 15;
    float v = 0.f;
    if (n == 0) {
        if (k < 30)       v = W[k];
        else if (k == 30) v = b2[0];
    }
    out[tid] = (bf16)v;
}

static __device__ void dev_pack_sel(int tid, bf16* out) {
    int i = tid & 7, lane = (tid >> 3) & 63, f = tid >> 9;
    int kt = f >> 1, nt = f & 1;
    int kloc = ((lane >> 4) * 8) + i;
    int n = 2 * (lane & 15) + nt;
    float v = (kloc == n && n < 30) ? ((kt & 1) ? -1.f : 1.f) : 0.f;
    out[tid] = (bf16)v;
}

// ===========================================================================
// setup_a: count (3125 blocks) + pack_all (186) + node_d (196) in ONE dispatch
// ===========================================================================
__global__ __launch_bounds__(256) void setup_a(
    const int* __restrict__ dst, int* __restrict__ counts,
    const float* __restrict__ Wm1_h, const float* __restrict__ bm1_h,
    const float* __restrict__ Wm1_o, const float* __restrict__ bm1_o,
    const float* __restrict__ Wm2_h, const float* __restrict__ bm2_h,
    const float* __restrict__ Wm2_o, const float* __restrict__ bm2_o,
    const float* __restrict__ W2_h,  const float* __restrict__ b2_h,
    const float* __restrict__ W2_o,  const float* __restrict__ b2_o,
    const float* __restrict__ Wm1_d,
    bf16* __restrict__ Wm1B_h, bf16* __restrict__ Wm1B_o,
    bf16* __restrict__ Wm2B_h, bf16* __restrict__ Wm2B_o,
    bf16* __restrict__ W2B_h,  bf16* __restrict__ W2B_o,
    bf16* __restrict__ SelB,   float* __restrict__ Wm1T_d,
    const float* __restrict__ features, const float* __restrict__ W1_d,
    const float* __restrict__ b1_d, float* __restrict__ bufA) {
    int b = blockIdx.x, t = threadIdx.x;
    if (b < 3125) {                                  // count
        int e = b * 256 + t;
        if (e < N_EDGES) atomicAdd(&counts[dst[e]], 1);
    } else if (b < 3311) {                           // pack_all
        int pb = b - 3125;
        if (pb < 52)       dev_pack_wm1(pb * 256 + t, Wm1_h, bm1_h, Wm1B_h);
        else if (pb < 104) dev_pack_wm1((pb - 52) * 256 + t, Wm1_o, bm1_o, Wm1B_o);
        else if (pb < 132) dev_pack_wm2((pb - 104) * 256 + t, Wm2_h, bm2_h, Wm2B_h);
        else if (pb < 160) dev_pack_wm2((pb - 132) * 256 + t, Wm2_o, bm2_o, Wm2B_o);
        else if (pb < 164) dev_pack_w2h((pb - 160) * 256 + t, W2_h, b2_h, W2B_h);
        else if (pb < 166) dev_pack_w2o((pb - 164) * 256 + t, W2_o, b2_o, W2B_o);
        else if (pb < 182) dev_pack_sel((pb - 166) * 256 + t, SelB);
        else {
            int i = (pb - 182) * 256 + t;
            if (i < C_MSG * 4) Wm1T_d[i] = Wm1_d[(i & 3) * C_MSG + (i >> 2)];
        }
    } else {                                         // node term, layer d
        int n = (b - 3311) * 256 + t;
        if (n < N_NODES) {
            float xv = features[n];
            for (int o = 0; o < 30; ++o)
                bufA[n * 30 + o] = fmaf(xv, W1_d[o], b1_d[o]);
        }
    }
}

// Parallel scan over counts
__global__ __launch_bounds__(256) void scan_kernel(const int* __restrict__ counts,
                                                   int* __restrict__ offsets,
                                                   int* __restrict__ cursor) {
    __shared__ int ws[4];
    const int b = blockIdx.x, t = threadIdx.x;
    const int lane = t & 63, wv = t >> 6;
    int acc = 0;
    for (int i = t; i < b * 256; i += 256) acc += counts[i];
#pragma unroll
    for (int d = 32; d > 0; d >>= 1) acc += __shfl_xor(acc, d);
    if (lane == 0) ws[wv] = acc;
    __syncthreads();
    int base = ws[0] + ws[1] + ws[2] + ws[3];
    __syncthreads();
    int i = b * 256 + t;
    int v = (i < N_NODES) ? counts[i] : 0;
    int inc = v;
#pragma unroll
    for (int d = 1; d < 64; d <<= 1) {
        int u = __shfl_up(inc, d);
        if (lane >= d) inc += u;
    }
    if (lane == 63) ws[wv] = inc;
    __syncthreads();
    int waveoff = 0;
    for (int k = 0; k < wv; ++k) waveoff += ws[k];
    int excl = base + waveoff + inc - v;
    if (i < N_NODES) { offsets[i] = excl; cursor[i] = excl; }
    if (i == N_NODES - 1) offsets[N_NODES] = excl + v;
}

// scatter: ONE int4 stream {src, dst, ewbf, perm} in perm order
__global__ __launch_bounds__(256) void scatter_kernel(
    const int* __restrict__ src, const int* __restrict__ dst,
    const float* __restrict__ ew, int* __restrict__ cursor,
    int4* __restrict__ edata) {
    int e = blockIdx.x * 256 + threadIdx.x;
    if (e < N_EDGES) {
        int d = dst[e];
        int p = atomicAdd(&cursor[d], 1);
        edata[p] = make_int4(src[e], d, (int)pk_bf16(ew[2 * e], ew[2 * e + 1]), e);
    }
}

// ===========================================================================
// Layer-d edge kernel (CIN=1): full-fp32 VALU path, perm order
// ===========================================================================
__global__ __launch_bounds__(256) void edge_d_kernel(
    const float* __restrict__ x, const int4* __restrict__ edata,
    const float* __restrict__ ew,
    const float* __restrict__ Wm1T, const float* __restrict__ bm1,
    const float* __restrict__ Wm2, const float* __restrict__ bm2,
    const float* __restrict__ W2, const float* __restrict__ b2, bf16* __restrict__ msg)
{
    int t = blockIdx.x * 256 + threadIdx.x;
    int4 ed = edata[t];
    float xi = x[ed.y], xj = x[ed.x];
    int p = ed.w;
    float e0 = ew[2 * p], e1 = ew[2 * p + 1];
    float m = bm2[0];
    for (int j = 0; j < C_MSG; ++j) {
        const float* __restrict__ wr = Wm1T + j * 4;
        float h = bm1[j];
        h = fmaf(xi, wr[0], h);
        h = fmaf(xj, wr[1], h);
        h = fmaf(e0, wr[2], h);
        h = fmaf(e1, wr[3], h);
        h = fmaxf(h, 0.f);
        m = fmaf(h, Wm2[j], m);
    }
    float md = m * (xi - xj);
    for (int o = 0; o < 15; ++o) {
        float f0 = fmaf(md, W2[2 * o], b2[2 * o]);
        float f1 = fmaf(md, W2[2 * o + 1], b2[2 * o + 1]);
        *(unsigned int*)(msg + (size_t)t * 32 + 2 * o) = pk_bf16(f0, f1);
    }
}

// ===========================================================================
// MFMA edge kernel v12: chunk-fused GEMM1/GEMM2, 12.3KB LDS (was 29.7KB).
//  R3 post-mortem: three structurally different versions (N-split 42% occ,
//  M-split 40%, 4-tile pipeline 20%) all land at ~105us with every pipe
//  <30% busy and FETCH/VALU reductions having zero effect -> LATENCY-bound
//  with too few resident waves. The only untouched resource: the 29.7KB
//  hp[64][232] LDS buffer capping blocks/CU at 5.
//  v12: GEMM1 pair p produces EXACTLY the 32 cols GEMM2's kt=p consumes.
//  Fuse them per-chunk through tiny wave-private 16x32 buffers:
//   - chunks A/B double-buffered by p parity (pair p+1 GEMM1 overlaps
//     pair p read turnaround); cP holds the leftover tile with const pad
//     cols (bias row) written once per kernel.
//   - XOR-swizzle 16B slots (slot ^= row&3): b128 chunk reads are
//     perfectly bank-uniform (8 accesses/bank over min-8 cycles).
//   - LDS/block 29696 -> 12288 (3KB/wave): LDS cap 5 -> 13 blocks/CU.
//   - a2/a3 (lo rows) + selector GEMM moved AFTER the p-loop: same 128B
//     line as A0/A1 -> L1-hot reload; cuts hot-loop VGPR pressure.
//   - __launch_bounds__(256,6): target 6 waves/SIMD. Spill tripwire:
//     WRITE_SIZE must stay 50MB.
//  m0/m1 accumulate in the same kt=0..6 order; every accumulator's op
//  sequence unchanged -> bit-identical output.
// ===========================================================================
template<int COUT>
__global__ __launch_bounds__(256, 6) void edge_mfma(
    const bf16* __restrict__ xc, const int4* __restrict__ edata,
    const bf16* __restrict__ Wm1B, const bf16* __restrict__ SelB,
    const bf16* __restrict__ Wm2B, const bf16* __restrict__ W2B,
    bf16* __restrict__ msg)
{
    __shared__ __align__(16) bf16 smem[4][3][512];   // per-wave: chunkA/B + cP

    const int tid = threadIdx.x, w = tid >> 6, lane = tid & 63;
    const int col = lane & 15, quad = lane >> 4, row0 = quad * 4;
    const int blk = blockIdx.x * 64;
    const int ebase = blk + w * 16;

    char* cbase = (char*)&smem[w][0][0];
    char* cA = cbase;
    char* cB = cbase + 1024;
    char* cP = cbase + 2048;

    // cP pad slots 1..3 (global cols 200..223): slot1 elem0 = bm2 bias row
    // marker (1.0), rest 0. Written once; p6 only rewrites slot 0.
    if (lane < 48) {
        int r = lane / 3, s = 1 + (lane - r * 3);
        bf16x8 z = {};
        if (s == 1) z[0] = (bf16)1.f;
        *(bf16x8*)(cP + r * 64 + ((s << 4) ^ ((r & 3) << 4))) = z;
    }

    // ---- own 16 edges: hi-row A-frags ----
    int4 ed = edata[ebase + col];
    bf16x8 A0 = *(const bf16x8*)(xc + (size_t)ed.y * 64 + quad * 8);
    bf16x8 A1 = *(const bf16x8*)(xc + (size_t)ed.x * 64 + quad * 8);
    if (quad == 3) {
        union { unsigned int u; bf16 b[2]; } cv;
        cv.u = (unsigned int)ed.z;
        A1[6] = cv.b[0];
        A1[7] = cv.b[1];
    }

    // ---- fused GEMM1/GEMM2: pair p -> chunk -> kt=p accumulation ----
    f32x4 m0 = {0.f, 0.f, 0.f, 0.f}, m1 = {0.f, 0.f, 0.f, 0.f};
#pragma unroll
    for (int p = 0; p < 6; ++p) {
        char* cb = (p & 1) ? cB : cA;
        const bf16* Wf = Wm1B + (size_t)(4 * p) * 512 + lane * 8;
        bf16x8 be0 = *(const bf16x8*)(Wf);
        bf16x8 be1 = *(const bf16x8*)(Wf + 512);
        bf16x8 bo0 = *(const bf16x8*)(Wf + 1024);
        bf16x8 bo1 = *(const bf16x8*)(Wf + 1536);
        f32x4 ae = {0.f, 0.f, 0.f, 0.f}, ao = {0.f, 0.f, 0.f, 0.f};
        ae = MF(A0, be0, ae);
        ae = MF(A1, be1, ae);
        ao = MF(A0, bo0, ao);
        ao = MF(A1, bo1, ao);
#pragma unroll
        for (int rg = 0; rg < 4; ++rg) {
            int row = row0 + rg, wb = 4 * col;
            unsigned int u = pk_bf16(fmaxf(ae[rg], 0.f), fmaxf(ao[rg], 0.f));
            *(unsigned int*)(cb + row * 64 + ((wb & 48) ^ ((row & 3) << 4)) +
                             (wb & 15)) = u;
        }
        bf16x8 a = *(const bf16x8*)(cb + col * 64 +
                                    ((quad << 4) ^ ((col & 3) << 4)));
        m0 = MF(a, *(const bf16x8*)(Wm2B + (size_t)p * 512 + lane * 8), m0);
        m1 = MF(a, *(const bf16x8*)(Wm2B + (size_t)(7 + p) * 512 + lane * 8), m1);
    }
    {   // leftover N-tile 12 (kt=6): cols 192..199 real, pad const in cP
        const bf16* Wf = Wm1B + (size_t)24 * 512 + lane * 8;
        bf16x8 b0 = *(const bf16x8*)(Wf);
        bf16x8 b1 = *(const bf16x8*)(Wf + 512);
        f32x4 acc = {0.f, 0.f, 0.f, 0.f};
        acc = MF(A0, b0, acc);
        acc = MF(A1, b1, acc);
        if (col < 8) {
#pragma unroll
            for (int rg = 0; rg < 4; ++rg) {
                int row = row0 + rg;
                *(bf16*)(cP + row * 64 + ((row & 3) << 4) + 2 * col) =
                    (bf16)fmaxf(acc[rg], 0.f);
            }
        }
        bf16x8 a = *(const bf16x8*)(cP + col * 64 +
                                    ((quad << 4) ^ ((col & 3) << 4)));
        m0 = MF(a, *(const bf16x8*)(Wm2B + (size_t)6 * 512 + lane * 8), m0);
        m1 = MF(a, *(const bf16x8*)(Wm2B + (size_t)13 * 512 + lane * 8), m1);
    }

    // ---- lo-row frags (same 128B lines as A0/A1 -> L1-hot) + selector ----
    bf16x8 a2 = *(const bf16x8*)(xc + (size_t)ed.y * 64 + 32 + quad * 8);
    bf16x8 a3 = *(const bf16x8*)(xc + (size_t)ed.x * 64 + 32 + quad * 8);
    f32x4 dc0 = {0.f, 0.f, 0.f, 0.f}, dc1 = {0.f, 0.f, 0.f, 0.f};
    dc0 = MF(A0, *(const bf16x8*)(SelB + (size_t)0 * 512 + lane * 8), dc0);
    dc1 = MF(A0, *(const bf16x8*)(SelB + (size_t)1 * 512 + lane * 8), dc1);
    dc0 = MF(A1, *(const bf16x8*)(SelB + (size_t)2 * 512 + lane * 8), dc0);
    dc1 = MF(A1, *(const bf16x8*)(SelB + (size_t)3 * 512 + lane * 8), dc1);
    dc0 = MF(a2, *(const bf16x8*)(SelB + (size_t)4 * 512 + lane * 8), dc0);
    dc1 = MF(a2, *(const bf16x8*)(SelB + (size_t)5 * 512 + lane * 8), dc1);
    dc0 = MF(a3, *(const bf16x8*)(SelB + (size_t)6 * 512 + lane * 8), dc0);
    dc1 = MF(a3, *(const bf16x8*)(SelB + (size_t)7 * 512 + lane * 8), dc1);

    // ---- md = m*diff -> chunkA -> GEMM3 A-frag ----
#pragma unroll
    for (int rg = 0; rg < 4; ++rg) {
        int row = row0 + rg, wb = 4 * col;
        unsigned int u = (col == 15) ? pk_bf16(1.f, 0.f)
                                     : pk_bf16(m0[rg] * dc0[rg], m1[rg] * dc1[rg]);
        *(unsigned int*)(cA + row * 64 + ((wb & 48) ^ ((row & 3) << 4)) +
                         (wb & 15)) = u;
    }
    bf16x8 am = *(const bf16x8*)(cA + col * 64 +
                                 ((quad << 4) ^ ((col & 3) << 4)));

    // ---- GEMM3: md[16x32] @ W2[32xN] -> msg ----
    if (COUT == 30) {
        bf16x8 b0 = *(const bf16x8*)(W2B + lane * 8);
        bf16x8 b1 = *(const bf16x8*)(W2B + 512 + lane * 8);
        f32x4 c0 = {0.f, 0.f, 0.f, 0.f}, c1 = {0.f, 0.f, 0.f, 0.f};
        c0 = MF(am, b0, c0);
        c1 = MF(am, b1, c1);
#pragma unroll
        for (int rg = 0; rg < 4; ++rg)
            *(unsigned int*)(msg + (size_t)(ebase + row0 + rg) * 32 + 2 * col) =
                pk_bf16(c0[rg], c1[rg]);
    } else {
        // COUT=1: compact msg1[e] layout — one 8B store per col==0 lane
        bf16x8 b0 = *(const bf16x8*)(W2B + lane * 8);
        f32x4 c0 = {0.f, 0.f, 0.f, 0.f};
        c0 = MF(am, b0, c0);
        if (col == 0) {
            union { bf16 h[4]; unsigned long long u; } pk4;
#pragma unroll
            for (int rg = 0; rg < 4; ++rg) pk4.h[rg] = (bf16)c0[rg];
            *(unsigned long long*)(msg + (ebase + row0)) = pk4.u;
        }
    }
}

// ===========================================================================
// Fused aggregation + next node term. 16 lanes per node; width-16 shuffles;
// fma order identical to the original node_kernel -> numerically identical.
// Writes the merged xc row: hi (bf16 x) at cols [0,32), lo residual at [32,64).
// ===========================================================================
template<int CNEXT>
__global__ __launch_bounds__(256) void agg_fused(
    const bf16* __restrict__ msg, const int* __restrict__ offsets,
    const float* __restrict__ bufc,
    const float* __restrict__ W1n, const float* __restrict__ b1n,
    float* __restrict__ bufn,
    bf16* __restrict__ xc) {
    int gh = (blockIdx.x * 256 + threadIdx.x) >> 4;
    int lane = threadIdx.x & 15;
    int s0 = offsets[gh], s1 = offsets[gh + 1];
    float r0 = 0.f, r1 = 0.f;
    if (lane < 15) {
        float v0 = 0.f, v1 = 0.f;
        const unsigned int* mp =
            (const unsigned int*)(msg + (size_t)s0 * 32 + lane * 2);
        int cnt = s1 - s0, j = 0;
        for (; j + 4 <= cnt; j += 4) {
            unsigned int u0 = mp[(size_t)(j + 0) * 16];
            unsigned int u1 = mp[(size_t)(j + 1) * 16];
            unsigned int u2 = mp[(size_t)(j + 2) * 16];
            unsigned int u3 = mp[(size_t)(j + 3) * 16];
            union { unsigned int u; bf16 b[2]; } c0, c1, c2, c3;
            c0.u = u0; c1.u = u1; c2.u = u2; c3.u = u3;
            v0 += (float)c0.b[0]; v1 += (float)c0.b[1];
            v0 += (float)c1.b[0]; v1 += (float)c1.b[1];
            v0 += (float)c2.b[0]; v1 += (float)c2.b[1];
            v0 += (float)c3.b[0]; v1 += (float)c3.b[1];
        }
        for (; j < cnt; ++j) {
            union { unsigned int u; bf16 b[2]; } cv;
            cv.u = mp[(size_t)j * 16];
            v0 += (float)cv.b[0]; v1 += (float)cv.b[1];
        }
        float f0 = bufc[(size_t)gh * 30 + 2 * lane] + v0;
        float f1 = bufc[(size_t)gh * 30 + 2 * lane + 1] + v1;
        r0 = fmaxf(f0, 0.f);
        r1 = fmaxf(f1, 0.f);
        bf16 h0 = (bf16)r0, h1 = (bf16)r1;
        union { bf16 h[2]; unsigned int u; } hi;
        hi.h[0] = h0; hi.h[1] = h1;
        *(unsigned int*)(xc + (size_t)gh * 64 + 2 * lane) = hi.u;
        *(unsigned int*)(xc + (size_t)gh * 64 + 32 + 2 * lane) =
            pk_bf16(r0 - (float)h0, r1 - (float)h1);
    } else {
        *(unsigned int*)(xc + (size_t)gh * 64 + 30) = pk_bf16(1.f, 0.f);
        *(unsigned int*)(xc + (size_t)gh * 64 + 62) = 0u;
    }
    // ---- next node term (fma order == original node_kernel) ----
    if (CNEXT == 30) {
        float acc0 = 0.f, acc1 = 0.f;
        if (lane < 15) { acc0 = b1n[2 * lane]; acc1 = b1n[2 * lane + 1]; }
        for (int k2 = 0; k2 < 15; ++k2) {
            float rk0 = __shfl(r0, k2, 16);
            float rk1 = __shfl(r1, k2, 16);
            if (lane < 15) {
                const float* w0 = W1n + (2 * k2) * 30 + 2 * lane;
                const float* w1 = W1n + (2 * k2 + 1) * 30 + 2 * lane;
                acc0 = fmaf(rk0, w0[0], acc0);
                acc1 = fmaf(rk0, w0[1], acc1);
                acc0 = fmaf(rk1, w1[0], acc0);
                acc1 = fmaf(rk1, w1[1], acc1);
            }
        }
        if (lane < 15) {
            bufn[(size_t)gh * 30 + 2 * lane] = acc0;
            bufn[(size_t)gh * 30 + 2 * lane + 1] = acc1;
        }
    } else {
        float acc = b1n[0];
        for (int k2 = 0; k2 < 15; ++k2) {
            float rk0 = __shfl(r0, k2, 16);
            float rk1 = __shfl(r1, k2, 16);
            acc = fmaf(rk0, W1n[2 * k2], acc);
            acc = fmaf(rk1, W1n[2 * k2 + 1], acc);
        }
        if (lane == 0) bufn[gh] = acc;
    }
}

// Final aggregation, compact msg1[e]: out[gh] += sum (same lane->j order)
__global__ __launch_bounds__(256) void agg_last(const bf16* __restrict__ msg1,
                                                const int* __restrict__ offsets,
                                                float* __restrict__ out) {
    int gh = (blockIdx.x * 256 + threadIdx.x) >> 5;
    int lane = threadIdx.x & 31;
    int s0 = offsets[gh], s1 = offsets[gh + 1];
    float v = 0.f;
    for (int j = s0 + lane; j < s1; j += 32) v += (float)msg1[j];
#pragma unroll
    for (int o = 16; o > 0; o >>= 1) v += __shfl_xor(v, o);
    if (lane == 0) out[gh] += v;
}

// ===========================================================================
extern "C" void kernel_launch(void* const* d_in, const int* in_sizes, int n_in,
                              void* d_out, int out_size, void* d_ws, size_t ws_size,
                              hipStream_t stream) {
    const float* features = (const float*)d_in[0];
    const int*   edges    = (const int*)d_in[1];
    const float* ew       = (const float*)d_in[2];

    const float* W1_d  = (const float*)d_in[3];
    const float* b1_d  = (const float*)d_in[4];
    const float* Wm1_d = (const float*)d_in[5];
    const float* bm1_d = (const float*)d_in[6];
    const float* Wm2_d = (const float*)d_in[7];
    const float* bm2_d = (const float*)d_in[8];
    const float* W2_d  = (const float*)d_in[9];
    const float* b2_d  = (const float*)d_in[10];

    const float* W1_h  = (const float*)d_in[11];
    const float* b1_h  = (const float*)d_in[12];
    const float* Wm1_h = (const float*)d_in[13];
    const float* bm1_h = (const float*)d_in[14];
    const float* Wm2_h = (const float*)d_in[15];
    const float* bm2_h = (const float*)d_in[16];
    const float* W2_h  = (const float*)d_in[17];
    const float* b2_h  = (const float*)d_in[18];

    const float* W1_o  = (const float*)d_in[19];
    const float* b1_o  = (const float*)d_in[20];
    const float* Wm1_o = (const float*)d_in[21];
    const float* bm1_o = (const float*)d_in[22];
    const float* Wm2_o = (const float*)d_in[23];
    const float* bm2_o = (const float*)d_in[24];
    const float* W2_o  = (const float*)d_in[25];
    const float* b2_o  = (const float*)d_in[26];

    const int* src = edges;
    const int* dst = edges + N_EDGES;
    float* out = (float*)d_out;

    // ---- workspace carve-up ----
    char* p = (char*)d_ws;
    auto alloc = [&](size_t bytes) { char* r = p; p += (bytes + 63) & ~(size_t)63; return r; };
    float* bufA    = (float*)alloc((size_t)N_NODES * 30 * 4);
    float* bufB    = (float*)alloc((size_t)N_NODES * 30 * 4);
    bf16*  msg     = (bf16*) alloc((size_t)N_EDGES * 32 * 2);
    bf16*  xc      = (bf16*) alloc((size_t)N_NODES * 64 * 2);
    int*   counts  = (int*)  alloc((size_t)N_NODES * 4);
    int*   offsets = (int*)  alloc((size_t)(N_NODES + 1) * 4);
    int*   cursor  = (int*)  alloc((size_t)N_NODES * 4);
    int4*  edata   = (int4*) alloc((size_t)N_EDGES * 16);
    float* Wm1T_d  = (float*)alloc((size_t)C_MSG * 4 * 4);
    bf16*  Wm1B_h  = (bf16*) alloc((size_t)26 * 512 * 2);
    bf16*  Wm1B_o  = (bf16*) alloc((size_t)26 * 512 * 2);
    bf16*  Wm2B_h  = (bf16*) alloc((size_t)14 * 512 * 2);
    bf16*  Wm2B_o  = (bf16*) alloc((size_t)14 * 512 * 2);
    bf16*  W2B_h   = (bf16*) alloc((size_t)2 * 512 * 2);
    bf16*  W2B_o   = (bf16*) alloc((size_t)1 * 512 * 2);
    bf16*  SelB    = (bf16*) alloc((size_t)8 * 512 * 2);

    // ---- setup ----
    hipMemsetAsync(counts, 0, (size_t)N_NODES * 4, stream);
    setup_a<<<3507, 256, 0, stream>>>(dst, counts,
        Wm1_h, bm1_h, Wm1_o, bm1_o, Wm2_h, bm2_h, Wm2_o, bm2_o,
        W2_h, b2_h, W2_o, b2_o, Wm1_d,
        Wm1B_h, Wm1B_o, Wm2B_h, Wm2B_o, W2B_h, W2B_o, SelB, Wm1T_d,
        features, W1_d, b1_d, bufA);
    scan_kernel<<<(N_NODES + 255) / 256, 256, 0, stream>>>(counts, offsets, cursor);
    scatter_kernel<<<N_EDGES / 256, 256, 0, stream>>>(src, dst, ew, cursor, edata);

    dim3 tb(256);
    dim3 eb_mfma(N_EDGES / 64);    // 1 tile of 16 edges per wave
    dim3 eb_valu(N_EDGES / 256);
    dim3 ab16(N_NODES * 16 / 256);
    dim3 ab32(N_NODES * 32 / 256);

    // ---- layer d ----
    edge_d_kernel<<<eb_valu, tb, 0, stream>>>(features, edata, ew,
        Wm1T_d, bm1_d, Wm2_d, bm2_d, W2_d, b2_d, msg);
    agg_fused<30><<<ab16, tb, 0, stream>>>(msg, offsets, bufA, W1_h, b1_h, bufB, xc);

    // ---- h1 ----
    edge_mfma<30><<<eb_mfma, tb, 0, stream>>>(xc, edata,
        Wm1B_h, SelB, Wm2B_h, W2B_h, msg);
    agg_fused<30><<<ab16, tb, 0, stream>>>(msg, offsets, bufB, W1_h, b1_h, bufA, xc);

    // ---- h2 ----
    edge_mfma<30><<<eb_mfma, tb, 0, stream>>>(xc, edata,
        Wm1B_h, SelB, Wm2B_h, W2B_h, msg);
    agg_fused<30><<<ab16, tb, 0, stream>>>(msg, offsets, bufA, W1_h, b1_h, bufB, xc);

    // ---- h3 (next node term = output layer -> writes d_out) ----
    edge_mfma<30><<<eb_mfma, tb, 0, stream>>>(xc, edata,
        Wm1B_h, SelB, Wm2B_h, W2B_h, msg);
    agg_fused<1><<<ab16, tb, 0, stream>>>(msg, offsets, bufB, W1_o, b1_o, out, xc);

    // ---- output layer (compact msg1) ----
    edge_mfma<1><<<eb_mfma, tb, 0, stream>>>(xc, edata,
        Wm1B_o, SelB, Wm2B_o, W2B_o, msg);
    agg_last<<<ab32, tb, 0, stream>>>(msg, offsets, out);
}

// Round 5
// 685.925 us; speedup vs baseline: 2.3712x; 1.0685x over previous
//
#include <hip/hip_runtime.h>

#define N_NODES 50000
#define N_EDGES 800000
#define C_MSG 200

typedef __bf16 bf16;
typedef __attribute__((ext_vector_type(8))) __bf16 bf16x8;
typedef __attribute__((ext_vector_type(4))) float f32x4;

static __device__ __forceinline__ unsigned int pk_bf16(float a, float b) {
    union { bf16 h[2]; unsigned int u; } cv;
    cv.h[0] = (bf16)a; cv.h[1] = (bf16)b;
    return cv.u;
}

static __device__ __forceinline__ f32x4 MF(bf16x8 a, bf16x8 b, f32x4 c) {
    return __builtin_amdgcn_mfma_f32_16x16x32_bf16(a, b, c, 0, 0, 0);
}

// ===========================================================================
// Weight packers (device fns) -> MFMA B-frag order (16x16x32), biases folded.
// Fragment f at out[f*512 + lane*8 + i]; lane holds B[k][n], k=kt*32+(lane>>4)*8+i.
// Paired N-tiles: pair p covers cols p*32 + 2*(lane&15) + parity.
// ===========================================================================
static __device__ void dev_pack_wm1(int tid, const float* W, const float* bm1,
                                    bf16* out) {
    int i = tid & 7, lane = (tid >> 3) & 63, rest = tid >> 9;
    int kt = rest % 2, t = rest / 2;
    int k = kt * 32 + ((lane >> 4) * 8) + i;
    int c = lane & 15;
    int n = (t < 12) ? ((t >> 1) * 32 + 2 * c + (t & 1)) : (192 + c);
    float v = 0.f;
    if (n < C_MSG) {
        if (k < 30)       v = W[k * C_MSG + n];
        else if (k == 30) v = bm1[n];
        else if (k >= 32) v = W[(k - 2) * C_MSG + n];
    }
    out[tid] = (bf16)v;
}

static __device__ void dev_pack_wm2(int tid, const float* W, const float* bm2,
                                    bf16* out) {
    int i = tid & 7, lane = (tid >> 3) & 63, rest = tid >> 9;
    int kt = rest % 7, nt = rest / 7;
    int k = kt * 32 + ((lane >> 4) * 8) + i;
    int n = 2 * (lane & 15) + nt;
    float v = 0.f;
    if (n < 30) {
        if (k < C_MSG)       v = W[k * 30 + n];
        else if (k == C_MSG) v = bm2[n];
    }
    out[tid] = (bf16)v;
}

static __device__ void dev_pack_w2h(int tid, const float* W, const float* b2,
                                    bf16* out) {
    int i = tid & 7, lane = (tid >> 3) & 63, nt = tid >> 9;
    int k = ((lane >> 4) * 8) + i;
    int n = 2 * (lane & 15) + nt;
    float v = 0.f;
    if (n < 30) {
        if (k < 30)       v = W[k * 30 + n];
        else if (k == 30) v = b2[n];
    }
    out[tid] = (bf16)v;
}

static __device__ void dev_pack_w2o(int tid, const float* W, const float* b2,
                                    bf16* out) {
    int i = tid & 7, lane = (tid >> 3) & 63;
    int k = ((lane >> 4) * 8) + i;
    int n = lane & 15;
    float v = 0.f;
    if (n == 0) {
        if (k < 30)       v = W[k];
        else if (k == 30) v = b2[0];
    }
    out[tid] = (bf16)v;
}

static __device__ void dev_pack_sel(int tid, bf16* out) {
    int i = tid & 7, lane = (tid >> 3) & 63, f = tid >> 9;
    int kt = f >> 1, nt = f & 1;
    int kloc = ((lane >> 4) * 8) + i;
    int n = 2 * (lane & 15) + nt;
    float v = (kloc == n && n < 30) ? ((kt & 1) ? -1.f : 1.f) : 0.f;
    out[tid] = (bf16)v;
}

// ===========================================================================
// setup_a: count (3125 blocks) + pack_all (186) + node_d (196) in ONE dispatch
// ===========================================================================
__global__ __launch_bounds__(256) void setup_a(
    const int* __restrict__ dst, int* __restrict__ counts,
    const float* __restrict__ Wm1_h, const float* __restrict__ bm1_h,
    const float* __restrict__ Wm1_o, const float* __restrict__ bm1_o,
    const float* __restrict__ Wm2_h, const float* __restrict__ bm2_h,
    const float* __restrict__ Wm2_o, const float* __restrict__ bm2_o,
    const float* __restrict__ W2_h,  const float* __restrict__ b2_h,
    const float* __restrict__ W2_o,  const float* __restrict__ b2_o,
    const float* __restrict__ Wm1_d,
    bf16* __restrict__ Wm1B_h, bf16* __restrict__ Wm1B_o,
    bf16* __restrict__ Wm2B_h, bf16* __restrict__ Wm2B_o,
    bf16* __restrict__ W2B_h,  bf16* __restrict__ W2B_o,
    bf16* __restrict__ SelB,   float* __restrict__ Wm1T_d,
    const float* __restrict__ features, const float* __restrict__ W1_d,
    const float* __restrict__ b1_d, float* __restrict__ bufA) {
    int b = blockIdx.x, t = threadIdx.x;
    if (b < 3125) {                                  // count
        int e = b * 256 + t;
        if (e < N_EDGES) atomicAdd(&counts[dst[e]], 1);
    } else if (b < 3311) {                           // pack_all
        int pb = b - 3125;
        if (pb < 52)       dev_pack_wm1(pb * 256 + t, Wm1_h, bm1_h, Wm1B_h);
        else if (pb < 104) dev_pack_wm1((pb - 52) * 256 + t, Wm1_o, bm1_o, Wm1B_o);
        else if (pb < 132) dev_pack_wm2((pb - 104) * 256 + t, Wm2_h, bm2_h, Wm2B_h);
        else if (pb < 160) dev_pack_wm2((pb - 132) * 256 + t, Wm2_o, bm2_o, Wm2B_o);
        else if (pb < 164) dev_pack_w2h((pb - 160) * 256 + t, W2_h, b2_h, W2B_h);
        else if (pb < 166) dev_pack_w2o((pb - 164) * 256 + t, W2_o, b2_o, W2B_o);
        else if (pb < 182) dev_pack_sel((pb - 166) * 256 + t, SelB);
        else {
            int i = (pb - 182) * 256 + t;
            if (i < C_MSG * 4) Wm1T_d[i] = Wm1_d[(i & 3) * C_MSG + (i >> 2)];
        }
    } else {                                         // node term, layer d
        int n = (b - 3311) * 256 + t;
        if (n < N_NODES) {
            float xv = features[n];
            for (int o = 0; o < 30; ++o)
                bufA[n * 30 + o] = fmaf(xv, W1_d[o], b1_d[o]);
        }
    }
}

// Parallel scan over counts
__global__ __launch_bounds__(256) void scan_kernel(const int* __restrict__ counts,
                                                   int* __restrict__ offsets,
                                                   int* __restrict__ cursor) {
    __shared__ int ws[4];
    const int b = blockIdx.x, t = threadIdx.x;
    const int lane = t & 63, wv = t >> 6;
    int acc = 0;
    for (int i = t; i < b * 256; i += 256) acc += counts[i];
#pragma unroll
    for (int d = 32; d > 0; d >>= 1) acc += __shfl_xor(acc, d);
    if (lane == 0) ws[wv] = acc;
    __syncthreads();
    int base = ws[0] + ws[1] + ws[2] + ws[3];
    __syncthreads();
    int i = b * 256 + t;
    int v = (i < N_NODES) ? counts[i] : 0;
    int inc = v;
#pragma unroll
    for (int d = 1; d < 64; d <<= 1) {
        int u = __shfl_up(inc, d);
        if (lane >= d) inc += u;
    }
    if (lane == 63) ws[wv] = inc;
    __syncthreads();
    int waveoff = 0;
    for (int k = 0; k < wv; ++k) waveoff += ws[k];
    int excl = base + waveoff + inc - v;
    if (i < N_NODES) { offsets[i] = excl; cursor[i] = excl; }
    if (i == N_NODES - 1) offsets[N_NODES] = excl + v;
}

// scatter: ONE int4 stream {src, dst, ewbf, perm} in perm order
__global__ __launch_bounds__(256) void scatter_kernel(
    const int* __restrict__ src, const int* __restrict__ dst,
    const float* __restrict__ ew, int* __restrict__ cursor,
    int4* __restrict__ edata) {
    int e = blockIdx.x * 256 + threadIdx.x;
    if (e < N_EDGES) {
        int d = dst[e];
        int p = atomicAdd(&cursor[d], 1);
        edata[p] = make_int4(src[e], d, (int)pk_bf16(ew[2 * e], ew[2 * e + 1]), e);
    }
}

// ===========================================================================
// Layer-d edge kernel (CIN=1): full-fp32 VALU path, perm order
// ===========================================================================
__global__ __launch_bounds__(256) void edge_d_kernel(
    const float* __restrict__ x, const int4* __restrict__ edata,
    const float* __restrict__ ew,
    const float* __restrict__ Wm1T, const float* __restrict__ bm1,
    const float* __restrict__ Wm2, const float* __restrict__ bm2,
    const float* __restrict__ W2, const float* __restrict__ b2, bf16* __restrict__ msg)
{
    int t = blockIdx.x * 256 + threadIdx.x;
    int4 ed = edata[t];
    float xi = x[ed.y], xj = x[ed.x];
    int p = ed.w;
    float e0 = ew[2 * p], e1 = ew[2 * p + 1];
    float m = bm2[0];
    for (int j = 0; j < C_MSG; ++j) {
        const float* __restrict__ wr = Wm1T + j * 4;
        float h = bm1[j];
        h = fmaf(xi, wr[0], h);
        h = fmaf(xj, wr[1], h);
        h = fmaf(e0, wr[2], h);
        h = fmaf(e1, wr[3], h);
        h = fmaxf(h, 0.f);
        m = fmaf(h, Wm2[j], m);
    }
    float md = m * (xi - xj);
    for (int o = 0; o < 15; ++o) {
        float f0 = fmaf(md, W2[2 * o], b2[2 * o]);
        float f1 = fmaf(md, W2[2 * o + 1], b2[2 * o + 1]);
        *(unsigned int*)(msg + (size_t)t * 32 + 2 * o) = pk_bf16(f0, f1);
    }
}

// ===========================================================================
// MFMA edge kernel v13: v12's chunk-fused structure + Wm1B/Wm2B staged in LDS.
//  R4 post-mortem: v8-v12 span occupancy 20-71%, FETCH 42-66MB, VALU 28-40%,
//  weight-load volume 122-200KB/64edges — dur pinned 101-106us through ALL
//  of it. Surviving invariant: latency-hiding capacity = (waves/SIMD) x
//  (spare VGPRs/wave for in-flight load results) — the register FILE per
//  SIMD is fixed, so ILP and TLP traded exactly inversely in every variant.
//  That capacity is spent mostly on ~40 per-tile WEIGHT fragment loads from
//  global (vmcnt + dest-VGPR economy), starving the compulsory random
//  gathers of memory-level parallelism.
//  v13: stage Wm1B (26KB) + Wm2B (14KB) into LDS once per block (10 vector
//  copies/thread + one __syncthreads); per-tile weight reads become
//  ds_read_b128 (lgkmcnt, ~120cyc, per-CU BW) and occupy ZERO global
//  in-flight slots. Global loads/tile: 55 -> 15 (edata + 4 gathers + SelB 8
//  + W2B 2; Sel/W2 are 10KB L1-resident). Chunk fusion, swizzle, MFMA order
//  all v12-verbatim -> bit-identical output.
//  LDS 53248B/block -> 3 blocks/CU; launch_bounds(256,4) keeps VGPR<=128 so
//  all 12 waves/CU fit. Spill tripwire: WRITE_SIZE must stay 50MB.
// ===========================================================================
template<int COUT>
__global__ __launch_bounds__(256, 4) void edge_mfma(
    const bf16* __restrict__ xc, const int4* __restrict__ edata,
    const bf16* __restrict__ Wm1B, const bf16* __restrict__ SelB,
    const bf16* __restrict__ Wm2B, const bf16* __restrict__ W2B,
    bf16* __restrict__ msg)
{
    // [0,13312): Wm1 26 frags; [13312,20480): Wm2 14 frags;
    // [20480,26624): 4 waves x 3 x 512 chunk buffers.  53248 B total.
    __shared__ __align__(16) bf16 smem[26624];
    bf16* Wm1L = smem;
    bf16* Wm2L = smem + 13312;

    const int tid = threadIdx.x, w = tid >> 6, lane = tid & 63;
    const int col = lane & 15, quad = lane >> 4, row0 = quad * 4;
    const int blk = blockIdx.x * 64;
    const int ebase = blk + w * 16;

    // ---- stage weights: 2560 x 16B chunks, 10 per thread ----
#pragma unroll
    for (int i = 0; i < 10; ++i) {
        int idx = tid + i * 256;
        bf16x8 v = (idx < 1664) ? *((const bf16x8*)Wm1B + idx)
                                : *((const bf16x8*)Wm2B + (idx - 1664));
        *((bf16x8*)smem + idx) = v;
    }
    __syncthreads();

    char* cbase = (char*)(smem + 20480 + w * 1536);
    char* cA = cbase;
    char* cB = cbase + 1024;
    char* cP = cbase + 2048;

    // cP pad slots 1..3 (global cols 200..223): slot1 elem0 = bm2 bias row
    // marker (1.0), rest 0. Written once; p6 only rewrites slot 0.
    if (lane < 48) {
        int r = lane / 3, s = 1 + (lane - r * 3);
        bf16x8 z = {};
        if (s == 1) z[0] = (bf16)1.f;
        *(bf16x8*)(cP + r * 64 + ((s << 4) ^ ((r & 3) << 4))) = z;
    }

    // ---- own 16 edges: hi-row A-frags ----
    int4 ed = edata[ebase + col];
    bf16x8 A0 = *(const bf16x8*)(xc + (size_t)ed.y * 64 + quad * 8);
    bf16x8 A1 = *(const bf16x8*)(xc + (size_t)ed.x * 64 + quad * 8);
    if (quad == 3) {
        union { unsigned int u; bf16 b[2]; } cv;
        cv.u = (unsigned int)ed.z;
        A1[6] = cv.b[0];
        A1[7] = cv.b[1];
    }

    // ---- fused GEMM1/GEMM2: pair p -> chunk -> kt=p accumulation ----
    f32x4 m0 = {0.f, 0.f, 0.f, 0.f}, m1 = {0.f, 0.f, 0.f, 0.f};
#pragma unroll
    for (int p = 0; p < 6; ++p) {
        char* cb = (p & 1) ? cB : cA;
        const bf16* Wf = Wm1L + (4 * p) * 512 + lane * 8;
        bf16x8 be0 = *(const bf16x8*)(Wf);
        bf16x8 be1 = *(const bf16x8*)(Wf + 512);
        bf16x8 bo0 = *(const bf16x8*)(Wf + 1024);
        bf16x8 bo1 = *(const bf16x8*)(Wf + 1536);
        f32x4 ae = {0.f, 0.f, 0.f, 0.f}, ao = {0.f, 0.f, 0.f, 0.f};
        ae = MF(A0, be0, ae);
        ae = MF(A1, be1, ae);
        ao = MF(A0, bo0, ao);
        ao = MF(A1, bo1, ao);
#pragma unroll
        for (int rg = 0; rg < 4; ++rg) {
            int row = row0 + rg, wb = 4 * col;
            unsigned int u = pk_bf16(fmaxf(ae[rg], 0.f), fmaxf(ao[rg], 0.f));
            *(unsigned int*)(cb + row * 64 + ((wb & 48) ^ ((row & 3) << 4)) +
                             (wb & 15)) = u;
        }
        bf16x8 a = *(const bf16x8*)(cb + col * 64 +
                                    ((quad << 4) ^ ((col & 3) << 4)));
        m0 = MF(a, *(const bf16x8*)(Wm2L + p * 512 + lane * 8), m0);
        m1 = MF(a, *(const bf16x8*)(Wm2L + (7 + p) * 512 + lane * 8), m1);
    }
    {   // leftover N-tile 12 (kt=6): cols 192..199 real, pad const in cP
        const bf16* Wf = Wm1L + 24 * 512 + lane * 8;
        bf16x8 b0 = *(const bf16x8*)(Wf);
        bf16x8 b1 = *(const bf16x8*)(Wf + 512);
        f32x4 acc = {0.f, 0.f, 0.f, 0.f};
        acc = MF(A0, b0, acc);
        acc = MF(A1, b1, acc);
        if (col < 8) {
#pragma unroll
            for (int rg = 0; rg < 4; ++rg) {
                int row = row0 + rg;
                *(bf16*)(cP + row * 64 + ((row & 3) << 4) + 2 * col) =
                    (bf16)fmaxf(acc[rg], 0.f);
            }
        }
        bf16x8 a = *(const bf16x8*)(cP + col * 64 +
                                    ((quad << 4) ^ ((col & 3) << 4)));
        m0 = MF(a, *(const bf16x8*)(Wm2L + 6 * 512 + lane * 8), m0);
        m1 = MF(a, *(const bf16x8*)(Wm2L + 13 * 512 + lane * 8), m1);
    }

    // ---- lo-row frags (same 128B lines as A0/A1 -> L1-hot) + selector ----
    bf16x8 a2 = *(const bf16x8*)(xc + (size_t)ed.y * 64 + 32 + quad * 8);
    bf16x8 a3 = *(const bf16x8*)(xc + (size_t)ed.x * 64 + 32 + quad * 8);
    f32x4 dc0 = {0.f, 0.f, 0.f, 0.f}, dc1 = {0.f, 0.f, 0.f, 0.f};
    dc0 = MF(A0, *(const bf16x8*)(SelB + (size_t)0 * 512 + lane * 8), dc0);
    dc1 = MF(A0, *(const bf16x8*)(SelB + (size_t)1 * 512 + lane * 8), dc1);
    dc0 = MF(A1, *(const bf16x8*)(SelB + (size_t)2 * 512 + lane * 8), dc0);
    dc1 = MF(A1, *(const bf16x8*)(SelB + (size_t)3 * 512 + lane * 8), dc1);
    dc0 = MF(a2, *(const bf16x8*)(SelB + (size_t)4 * 512 + lane * 8), dc0);
    dc1 = MF(a2, *(const bf16x8*)(SelB + (size_t)5 * 512 + lane * 8), dc1);
    dc0 = MF(a3, *(const bf16x8*)(SelB + (size_t)6 * 512 + lane * 8), dc0);
    dc1 = MF(a3, *(const bf16x8*)(SelB + (size_t)7 * 512 + lane * 8), dc1);

    // ---- md = m*diff -> chunkA -> GEMM3 A-frag ----
#pragma unroll
    for (int rg = 0; rg < 4; ++rg) {
        int row = row0 + rg, wb = 4 * col;
        unsigned int u = (col == 15) ? pk_bf16(1.f, 0.f)
                                     : pk_bf16(m0[rg] * dc0[rg], m1[rg] * dc1[rg]);
        *(unsigned int*)(cA + row * 64 + ((wb & 48) ^ ((row & 3) << 4)) +
                         (wb & 15)) = u;
    }
    bf16x8 am = *(const bf16x8*)(cA + col * 64 +
                                 ((quad << 4) ^ ((col & 3) << 4)));

    // ---- GEMM3: md[16x32] @ W2[32xN] -> msg ----
    if (COUT == 30) {
        bf16x8 b0 = *(const bf16x8*)(W2B + lane * 8);
        bf16x8 b1 = *(const bf16x8*)(W2B + 512 + lane * 8);
        f32x4 c0 = {0.f, 0.f, 0.f, 0.f}, c1 = {0.f, 0.f, 0.f, 0.f};
        c0 = MF(am, b0, c0);
        c1 = MF(am, b1, c1);
#pragma unroll
        for (int rg = 0; rg < 4; ++rg)
            *(unsigned int*)(msg + (size_t)(ebase + row0 + rg) * 32 + 2 * col) =
                pk_bf16(c0[rg], c1[rg]);
    } else {
        // COUT=1: compact msg1[e] layout — one 8B store per col==0 lane
        bf16x8 b0 = *(const bf16x8*)(W2B + lane * 8);
        f32x4 c0 = {0.f, 0.f, 0.f, 0.f};
        c0 = MF(am, b0, c0);
        if (col == 0) {
            union { bf16 h[4]; unsigned long long u; } pk4;
#pragma unroll
            for (int rg = 0; rg < 4; ++rg) pk4.h[rg] = (bf16)c0[rg];
            *(unsigned long long*)(msg + (ebase + row0)) = pk4.u;
        }
    }
}

// ===========================================================================
// Fused aggregation + next node term. 16 lanes per node; width-16 shuffles;
// fma order identical to the original node_kernel -> numerically identical.
// Writes the merged xc row: hi (bf16 x) at cols [0,32), lo residual at [32,64).
// ===========================================================================
template<int CNEXT>
__global__ __launch_bounds__(256) void agg_fused(
    const bf16* __restrict__ msg, const int* __restrict__ offsets,
    const float* __restrict__ bufc,
    const float* __restrict__ W1n, const float* __restrict__ b1n,
    float* __restrict__ bufn,
    bf16* __restrict__ xc) {
    int gh = (blockIdx.x * 256 + threadIdx.x) >> 4;
    int lane = threadIdx.x & 15;
    int s0 = offsets[gh], s1 = offsets[gh + 1];
    float r0 = 0.f, r1 = 0.f;
    if (lane < 15) {
        float v0 = 0.f, v1 = 0.f;
        const unsigned int* mp =
            (const unsigned int*)(msg + (size_t)s0 * 32 + lane * 2);
        int cnt = s1 - s0, j = 0;
        for (; j + 4 <= cnt; j += 4) {
            unsigned int u0 = mp[(size_t)(j + 0) * 16];
            unsigned int u1 = mp[(size_t)(j + 1) * 16];
            unsigned int u2 = mp[(size_t)(j + 2) * 16];
            unsigned int u3 = mp[(size_t)(j + 3) * 16];
            union { unsigned int u; bf16 b[2]; } c0, c1, c2, c3;
            c0.u = u0; c1.u = u1; c2.u = u2; c3.u = u3;
            v0 += (float)c0.b[0]; v1 += (float)c0.b[1];
            v0 += (float)c1.b[0]; v1 += (float)c1.b[1];
            v0 += (float)c2.b[0]; v1 += (float)c2.b[1];
            v0 += (float)c3.b[0]; v1 += (float)c3.b[1];
        }
        for (; j < cnt; ++j) {
            union { unsigned int u; bf16 b[2]; } cv;
            cv.u = mp[(size_t)j * 16];
            v0 += (float)cv.b[0]; v1 += (float)cv.b[1];
        }
        float f0 = bufc[(size_t)gh * 30 + 2 * lane] + v0;
        float f1 = bufc[(size_t)gh * 30 + 2 * lane + 1] + v1;
        r0 = fmaxf(f0, 0.f);
        r1 = fmaxf(f1, 0.f);
        bf16 h0 = (bf16)r0, h1 = (bf16)r1;
        union { bf16 h[2]; unsigned int u; } hi;
        hi.h[0] = h0; hi.h[1] = h1;
        *(unsigned int*)(xc + (size_t)gh * 64 + 2 * lane) = hi.u;
        *(unsigned int*)(xc + (size_t)gh * 64 + 32 + 2 * lane) =
            pk_bf16(r0 - (float)h0, r1 - (float)h1);
    } else {
        *(unsigned int*)(xc + (size_t)gh * 64 + 30) = pk_bf16(1.f, 0.f);
        *(unsigned int*)(xc + (size_t)gh * 64 + 62) = 0u;
    }
    // ---- next node term (fma order == original node_kernel) ----
    if (CNEXT == 30) {
        float acc0 = 0.f, acc1 = 0.f;
        if (lane < 15) { acc0 = b1n[2 * lane]; acc1 = b1n[2 * lane + 1]; }
        for (int k2 = 0; k2 < 15; ++k2) {
            float rk0 = __shfl(r0, k2, 16);
            float rk1 = __shfl(r1, k2, 16);
            if (lane < 15) {
                const float* w0 = W1n + (2 * k2) * 30 + 2 * lane;
                const float* w1 = W1n + (2 * k2 + 1) * 30 + 2 * lane;
                acc0 = fmaf(rk0, w0[0], acc0);
                acc1 = fmaf(rk0, w0[1], acc1);
                acc0 = fmaf(rk1, w1[0], acc0);
                acc1 = fmaf(rk1, w1[1], acc1);
            }
        }
        if (lane < 15) {
            bufn[(size_t)gh * 30 + 2 * lane] = acc0;
            bufn[(size_t)gh * 30 + 2 * lane + 1] = acc1;
        }
    } else {
        float acc = b1n[0];
        for (int k2 = 0; k2 < 15; ++k2) {
            float rk0 = __shfl(r0, k2, 16);
            float rk1 = __shfl(r1, k2, 16);
            acc = fmaf(rk0, W1n[2 * k2], acc);
            acc = fmaf(rk1, W1n[2 * k2 + 1], acc);
        }
        if (lane == 0) bufn[gh] = acc;
    }
}

// Final aggregation, compact msg1[e]: out[gh] += sum (same lane->j order)
__global__ __launch_bounds__(256) void agg_last(const bf16* __restrict__ msg1,
                                                const int* __restrict__ offsets,
                                                float* __restrict__ out) {
    int gh = (blockIdx.x * 256 + threadIdx.x) >> 5;
    int lane = threadIdx.x & 31;
    int s0 = offsets[gh], s1 = offsets[gh + 1];
    float v = 0.f;
    for (int j = s0 + lane; j < s1; j += 32) v += (float)msg1[j];
#pragma unroll
    for (int o = 16; o > 0; o >>= 1) v += __shfl_xor(v, o);
    if (lane == 0) out[gh] += v;
}

// ===========================================================================
extern "C" void kernel_launch(void* const* d_in, const int* in_sizes, int n_in,
                              void* d_out, int out_size, void* d_ws, size_t ws_size,
                              hipStream_t stream) {
    const float* features = (const float*)d_in[0];
    const int*   edges    = (const int*)d_in[1];
    const float* ew       = (const float*)d_in[2];

    const float* W1_d  = (const float*)d_in[3];
    const float* b1_d  = (const float*)d_in[4];
    const float* Wm1_d = (const float*)d_in[5];
    const float* bm1_d = (const float*)d_in[6];
    const float* Wm2_d = (const float*)d_in[7];
    const float* bm2_d = (const float*)d_in[8];
    const float* W2_d  = (const float*)d_in[9];
    const float* b2_d  = (const float*)d_in[10];

    const float* W1_h  = (const float*)d_in[11];
    const float* b1_h  = (const float*)d_in[12];
    const float* Wm1_h = (const float*)d_in[13];
    const float* bm1_h = (const float*)d_in[14];
    const float* Wm2_h = (const float*)d_in[15];
    const float* bm2_h = (const float*)d_in[16];
    const float* W2_h  = (const float*)d_in[17];
    const float* b2_h  = (const float*)d_in[18];

    const float* W1_o  = (const float*)d_in[19];
    const float* b1_o  = (const float*)d_in[20];
    const float* Wm1_o = (const float*)d_in[21];
    const float* bm1_o = (const float*)d_in[22];
    const float* Wm2_o = (const float*)d_in[23];
    const float* bm2_o = (const float*)d_in[24];
    const float* W2_o  = (const float*)d_in[25];
    const float* b2_o  = (const float*)d_in[26];

    const int* src = edges;
    const int* dst = edges + N_EDGES;
    float* out = (float*)d_out;

    // ---- workspace carve-up ----
    char* p = (char*)d_ws;
    auto alloc = [&](size_t bytes) { char* r = p; p += (bytes + 63) & ~(size_t)63; return r; };
    float* bufA    = (float*)alloc((size_t)N_NODES * 30 * 4);
    float* bufB    = (float*)alloc((size_t)N_NODES * 30 * 4);
    bf16*  msg     = (bf16*) alloc((size_t)N_EDGES * 32 * 2);
    bf16*  xc      = (bf16*) alloc((size_t)N_NODES * 64 * 2);
    int*   counts  = (int*)  alloc((size_t)N_NODES * 4);
    int*   offsets = (int*)  alloc((size_t)(N_NODES + 1) * 4);
    int*   cursor  = (int*)  alloc((size_t)N_NODES * 4);
    int4*  edata   = (int4*) alloc((size_t)N_EDGES * 16);
    float* Wm1T_d  = (float*)alloc((size_t)C_MSG * 4 * 4);
    bf16*  Wm1B_h  = (bf16*) alloc((size_t)26 * 512 * 2);
    bf16*  Wm1B_o  = (bf16*) alloc((size_t)26 * 512 * 2);
    bf16*  Wm2B_h  = (bf16*) alloc((size_t)14 * 512 * 2);
    bf16*  Wm2B_o  = (bf16*) alloc((size_t)14 * 512 * 2);
    bf16*  W2B_h   = (bf16*) alloc((size_t)2 * 512 * 2);
    bf16*  W2B_o   = (bf16*) alloc((size_t)1 * 512 * 2);
    bf16*  SelB    = (bf16*) alloc((size_t)8 * 512 * 2);

    // ---- setup ----
    hipMemsetAsync(counts, 0, (size_t)N_NODES * 4, stream);
    setup_a<<<3507, 256, 0, stream>>>(dst, counts,
        Wm1_h, bm1_h, Wm1_o, bm1_o, Wm2_h, bm2_h, Wm2_o, bm2_o,
        W2_h, b2_h, W2_o, b2_o, Wm1_d,
        Wm1B_h, Wm1B_o, Wm2B_h, Wm2B_o, W2B_h, W2B_o, SelB, Wm1T_d,
        features, W1_d, b1_d, bufA);
    scan_kernel<<<(N_NODES + 255) / 256, 256, 0, stream>>>(counts, offsets, cursor);
    scatter_kernel<<<N_EDGES / 256, 256, 0, stream>>>(src, dst, ew, cursor, edata);

    dim3 tb(256);
    dim3 eb_mfma(N_EDGES / 64);    // 1 tile of 16 edges per wave
    dim3 eb_valu(N_EDGES / 256);
    dim3 ab16(N_NODES * 16 / 256);
    dim3 ab32(N_NODES * 32 / 256);

    // ---- layer d ----
    edge_d_kernel<<<eb_valu, tb, 0, stream>>>(features, edata, ew,
        Wm1T_d, bm1_d, Wm2_d, bm2_d, W2_d, b2_d, msg);
    agg_fused<30><<<ab16, tb, 0, stream>>>(msg, offsets, bufA, W1_h, b1_h, bufB, xc);

    // ---- h1 ----
    edge_mfma<30><<<eb_mfma, tb, 0, stream>>>(xc, edata,
        Wm1B_h, SelB, Wm2B_h, W2B_h, msg);
    agg_fused<30><<<ab16, tb, 0, stream>>>(msg, offsets, bufB, W1_h, b1_h, bufA, xc);

    // ---- h2 ----
    edge_mfma<30><<<eb_mfma, tb, 0, stream>>>(xc, edata,
        Wm1B_h, SelB, Wm2B_h, W2B_h, msg);
    agg_fused<30><<<ab16, tb, 0, stream>>>(msg, offsets, bufA, W1_h, b1_h, bufB, xc);

    // ---- h3 (next node term = output layer -> writes d_out) ----
    edge_mfma<30><<<eb_mfma, tb, 0, stream>>>(xc, edata,
        Wm1B_h, SelB, Wm2B_h, W2B_h, msg);
    agg_fused<1><<<ab16, tb, 0, stream>>>(msg, offsets, bufB, W1_o, b1_o, out, xc);

    // ---- output layer (compact msg1) ----
    edge_mfma<1><<<eb_mfma, tb, 0, stream>>>(xc, edata,
        Wm1B_o, SelB, Wm2B_o, W2B_o, msg);
    agg_last<<<ab32, tb, 0, stream>>>(msg, offsets, out);
}

// Round 6
// 577.793 us; speedup vs baseline: 2.8149x; 1.1871x over previous
//
#include <hip/hip_runtime.h>

#define N_NODES 50000
#define N_EDGES 800000
#define C_MSG 200

typedef __bf16 bf16;
typedef __attribute__((ext_vector_type(8))) __bf16 bf16x8;
typedef __attribute__((ext_vector_type(4))) float f32x4;

static __device__ __forceinline__ unsigned int pk_bf16(float a, float b) {
    union { bf16 h[2]; unsigned int u; } cv;
    cv.h[0] = (bf16)a; cv.h[1] = (bf16)b;
    return cv.u;
}

static __device__ __forceinline__ f32x4 MF(bf16x8 a, bf16x8 b, f32x4 c) {
    return __builtin_amdgcn_mfma_f32_16x16x32_bf16(a, b, c, 0, 0, 0);
}

// ===========================================================================
// Weight packers (device fns) -> MFMA B-frag order (16x16x32), biases folded.
// Fragment f at out[f*512 + lane*8 + i]; lane holds B[k][n], k=kt*32+(lane>>4)*8+i.
// Paired N-tiles: pair p covers cols p*32 + 2*(lane&15) + parity.
// ===========================================================================
static __device__ void dev_pack_wm1(int tid, const float* W, const float* bm1,
                                    bf16* out) {
    int i = tid & 7, lane = (tid >> 3) & 63, rest = tid >> 9;
    int kt = rest % 2, t = rest / 2;
    int k = kt * 32 + ((lane >> 4) * 8) + i;
    int c = lane & 15;
    int n = (t < 12) ? ((t >> 1) * 32 + 2 * c + (t & 1)) : (192 + c);
    float v = 0.f;
    if (n < C_MSG) {
        if (k < 30)       v = W[k * C_MSG + n];
        else if (k == 30) v = bm1[n];
        else if (k >= 32) v = W[(k - 2) * C_MSG + n];
    }
    out[tid] = (bf16)v;
}

static __device__ void dev_pack_wm2(int tid, const float* W, const float* bm2,
                                    bf16* out) {
    int i = tid & 7, lane = (tid >> 3) & 63, rest = tid >> 9;
    int kt = rest % 7, nt = rest / 7;
    int k = kt * 32 + ((lane >> 4) * 8) + i;
    int n = 2 * (lane & 15) + nt;
    float v = 0.f;
    if (n < 30) {
        if (k < C_MSG)       v = W[k * 30 + n];
        else if (k == C_MSG) v = bm2[n];
    }
    out[tid] = (bf16)v;
}

static __device__ void dev_pack_w2h(int tid, const float* W, const float* b2,
                                    bf16* out) {
    int i = tid & 7, lane = (tid >> 3) & 63, nt = tid >> 9;
    int k = ((lane >> 4) * 8) + i;
    int n = 2 * (lane & 15) + nt;
    float v = 0.f;
    if (n < 30) {
        if (k < 30)       v = W[k * 30 + n];
        else if (k == 30) v = b2[n];
    }
    out[tid] = (bf16)v;
}

static __device__ void dev_pack_w2o(int tid, const float* W, const float* b2,
                                    bf16* out) {
    int i = tid & 7, lane = (tid >> 3) & 63;
    int k = ((lane >> 4) * 8) + i;
    int n = lane & 15;
    float v = 0.f;
    if (n == 0) {
        if (k < 30)       v = W[k];
        else if (k == 30) v = b2[0];
    }
    out[tid] = (bf16)v;
}

static __device__ void dev_pack_sel(int tid, bf16* out) {
    int i = tid & 7, lane = (tid >> 3) & 63, f = tid >> 9;
    int kt = f >> 1, nt = f & 1;
    int kloc = ((lane >> 4) * 8) + i;
    int n = 2 * (lane & 15) + nt;
    float v = (kloc == n && n < 30) ? ((kt & 1) ? -1.f : 1.f) : 0.f;
    out[tid] = (bf16)v;
}

// ===========================================================================
// setup_a: count (3125 blocks) + pack_all (186) + node_d (196) in ONE dispatch
// ===========================================================================
__global__ __launch_bounds__(256) void setup_a(
    const int* __restrict__ dst, int* __restrict__ counts,
    const float* __restrict__ Wm1_h, const float* __restrict__ bm1_h,
    const float* __restrict__ Wm1_o, const float* __restrict__ bm1_o,
    const float* __restrict__ Wm2_h, const float* __restrict__ bm2_h,
    const float* __restrict__ Wm2_o, const float* __restrict__ bm2_o,
    const float* __restrict__ W2_h,  const float* __restrict__ b2_h,
    const float* __restrict__ W2_o,  const float* __restrict__ b2_o,
    const float* __restrict__ Wm1_d,
    bf16* __restrict__ Wm1B_h, bf16* __restrict__ Wm1B_o,
    bf16* __restrict__ Wm2B_h, bf16* __restrict__ Wm2B_o,
    bf16* __restrict__ W2B_h,  bf16* __restrict__ W2B_o,
    bf16* __restrict__ SelB,   float* __restrict__ Wm1T_d,
    const float* __restrict__ features, const float* __restrict__ W1_d,
    const float* __restrict__ b1_d, float* __restrict__ bufA) {
    int b = blockIdx.x, t = threadIdx.x;
    if (b < 3125) {                                  // count
        int e = b * 256 + t;
        if (e < N_EDGES) atomicAdd(&counts[dst[e]], 1);
    } else if (b < 3311) {                           // pack_all
        int pb = b - 3125;
        if (pb < 52)       dev_pack_wm1(pb * 256 + t, Wm1_h, bm1_h, Wm1B_h);
        else if (pb < 104) dev_pack_wm1((pb - 52) * 256 + t, Wm1_o, bm1_o, Wm1B_o);
        else if (pb < 132) dev_pack_wm2((pb - 104) * 256 + t, Wm2_h, bm2_h, Wm2B_h);
        else if (pb < 160) dev_pack_wm2((pb - 132) * 256 + t, Wm2_o, bm2_o, Wm2B_o);
        else if (pb < 164) dev_pack_w2h((pb - 160) * 256 + t, W2_h, b2_h, W2B_h);
        else if (pb < 166) dev_pack_w2o((pb - 164) * 256 + t, W2_o, b2_o, W2B_o);
        else if (pb < 182) dev_pack_sel((pb - 166) * 256 + t, SelB);
        else {
            int i = (pb - 182) * 256 + t;
            if (i < C_MSG * 4) Wm1T_d[i] = Wm1_d[(i & 3) * C_MSG + (i >> 2)];
        }
    } else {                                         // node term, layer d
        int n = (b - 3311) * 256 + t;
        if (n < N_NODES) {
            float xv = features[n];
            for (int o = 0; o < 30; ++o)
                bufA[n * 30 + o] = fmaf(xv, W1_d[o], b1_d[o]);
        }
    }
}

// Parallel scan over counts
__global__ __launch_bounds__(256) void scan_kernel(const int* __restrict__ counts,
                                                   int* __restrict__ offsets,
                                                   int* __restrict__ cursor) {
    __shared__ int ws[4];
    const int b = blockIdx.x, t = threadIdx.x;
    const int lane = t & 63, wv = t >> 6;
    int acc = 0;
    for (int i = t; i < b * 256; i += 256) acc += counts[i];
#pragma unroll
    for (int d = 32; d > 0; d >>= 1) acc += __shfl_xor(acc, d);
    if (lane == 0) ws[wv] = acc;
    __syncthreads();
    int base = ws[0] + ws[1] + ws[2] + ws[3];
    __syncthreads();
    int i = b * 256 + t;
    int v = (i < N_NODES) ? counts[i] : 0;
    int inc = v;
#pragma unroll
    for (int d = 1; d < 64; d <<= 1) {
        int u = __shfl_up(inc, d);
        if (lane >= d) inc += u;
    }
    if (lane == 63) ws[wv] = inc;
    __syncthreads();
    int waveoff = 0;
    for (int k = 0; k < wv; ++k) waveoff += ws[k];
    int excl = base + waveoff + inc - v;
    if (i < N_NODES) { offsets[i] = excl; cursor[i] = excl; }
    if (i == N_NODES - 1) offsets[N_NODES] = excl + v;
}

// scatter: ONE int4 stream {src, dst, ewbf, perm} in perm order
__global__ __launch_bounds__(256) void scatter_kernel(
    const int* __restrict__ src, const int* __restrict__ dst,
    const float* __restrict__ ew, int* __restrict__ cursor,
    int4* __restrict__ edata) {
    int e = blockIdx.x * 256 + threadIdx.x;
    if (e < N_EDGES) {
        int d = dst[e];
        int p = atomicAdd(&cursor[d], 1);
        edata[p] = make_int4(src[e], d, (int)pk_bf16(ew[2 * e], ew[2 * e + 1]), e);
    }
}

// ===========================================================================
// Layer-d edge kernel (CIN=1): full-fp32 VALU path, perm order
// ===========================================================================
__global__ __launch_bounds__(256) void edge_d_kernel(
    const float* __restrict__ x, const int4* __restrict__ edata,
    const float* __restrict__ ew,
    const float* __restrict__ Wm1T, const float* __restrict__ bm1,
    const float* __restrict__ Wm2, const float* __restrict__ bm2,
    const float* __restrict__ W2, const float* __restrict__ b2, bf16* __restrict__ msg)
{
    int t = blockIdx.x * 256 + threadIdx.x;
    int4 ed = edata[t];
    float xi = x[ed.y], xj = x[ed.x];
    int p = ed.w;
    float e0 = ew[2 * p], e1 = ew[2 * p + 1];
    float m = bm2[0];
    for (int j = 0; j < C_MSG; ++j) {
        const float* __restrict__ wr = Wm1T + j * 4;
        float h = bm1[j];
        h = fmaf(xi, wr[0], h);
        h = fmaf(xj, wr[1], h);
        h = fmaf(e0, wr[2], h);
        h = fmaf(e1, wr[3], h);
        h = fmaxf(h, 0.f);
        m = fmaf(h, Wm2[j], m);
    }
    float md = m * (xi - xj);
    for (int o = 0; o < 15; ++o) {
        float f0 = fmaf(md, W2[2 * o], b2[2 * o]);
        float f1 = fmaf(md, W2[2 * o + 1], b2[2 * o + 1]);
        *(unsigned int*)(msg + (size_t)t * 32 + 2 * o) = pk_bf16(f0, f1);
    }
}

// ===========================================================================
// MFMA edge kernel v14: v13 (LDS-staged weights, chunk-fused, WORKED: -11%)
//  + 4-tiles-per-wave staging amortization + 2-deep gather prefetch.
//  R5 post-mortem: v13's win confirmed the in-flight-slot theory. Remaining
//  structural costs: (1) 40KB weight staging paid per 64 edges (12500
//  stagings/dispatch, 500MB L2-side traffic + serialized block-start
//  latency); (2) 5 compulsory gathers at tile start with ~2.4 waves/SIMD
//  to hide them.
//  v14: each wave processes 4 tiles (block = 256 edges, grid 3125):
//   - staging paid 4x less often (3125 stagings); edata loads issued
//     BEFORE the staging loop so they fly during it.
//   - v11's proven spill-free macro pipeline: tile t+1's x-frag gathers
//     issue before tile t's compute (2-deep, p/q register sets).
//   - __launch_bounds__(256,3): LDS (53248B) caps at 3 blocks/CU anyway;
//     VGPR cap ~170 removes spill risk of the fatter pipeline.
//  Per-tile op order is v13-verbatim (patch -> fused GEMM1/2 -> leftover ->
//  selector -> md -> GEMM3); a2/a3 prefetch moves only the LOAD, xc is
//  read-only in this kernel -> bit-identical output.
//  Spill tripwire: WRITE_SIZE must stay 50MB.
// ===========================================================================

#define LOAD_FRAGS(P, ED) do {                                                \
    const bf16* rd_ = xc + (size_t)(ED).y * 64 + quad * 8;                    \
    const bf16* rs_ = xc + (size_t)(ED).x * 64 + quad * 8;                    \
    P##A0 = *(const bf16x8*)(rd_);                                            \
    P##a2 = *(const bf16x8*)(rd_ + 32);                                       \
    P##A1 = *(const bf16x8*)(rs_);                                            \
    P##a3 = *(const bf16x8*)(rs_ + 32);                                       \
} while (0)

// Per-tile compute, v13 op order. Uses in-scope: Wm1L, Wm2L, cA, cB, cP,
// col, quad, row0, lane, SelB, W2B, msg, COUT.
#define COMPUTE_TILE(P, EDZ, EBASE) do {                                      \
    if (quad == 3) {                                                          \
        union { unsigned int u; bf16 b[2]; } cv_;                             \
        cv_.u = (unsigned int)(EDZ);                                          \
        P##A1[6] = cv_.b[0];                                                  \
        P##A1[7] = cv_.b[1];                                                  \
    }                                                                         \
    /* fused GEMM1/GEMM2: pair p_ -> chunk -> kt=p_ accumulation */           \
    f32x4 m0_ = {0.f,0.f,0.f,0.f}, m1_ = {0.f,0.f,0.f,0.f};                   \
    _Pragma("unroll")                                                         \
    for (int p_ = 0; p_ < 6; ++p_) {                                          \
        char* cb_ = (p_ & 1) ? cB : cA;                                       \
        const bf16* Wf_ = Wm1L + (4 * p_) * 512 + lane * 8;                   \
        bf16x8 be0_ = *(const bf16x8*)(Wf_);                                  \
        bf16x8 be1_ = *(const bf16x8*)(Wf_ + 512);                            \
        bf16x8 bo0_ = *(const bf16x8*)(Wf_ + 1024);                           \
        bf16x8 bo1_ = *(const bf16x8*)(Wf_ + 1536);                           \
        f32x4 ae_ = {0.f,0.f,0.f,0.f}, ao_ = {0.f,0.f,0.f,0.f};               \
        ae_ = MF(P##A0, be0_, ae_);                                           \
        ae_ = MF(P##A1, be1_, ae_);                                           \
        ao_ = MF(P##A0, bo0_, ao_);                                           \
        ao_ = MF(P##A1, bo1_, ao_);                                           \
        _Pragma("unroll")                                                     \
        for (int rg_ = 0; rg_ < 4; ++rg_) {                                   \
            int row_ = row0 + rg_, wb_ = 4 * col;                             \
            unsigned int u_ = pk_bf16(fmaxf(ae_[rg_],0.f), fmaxf(ao_[rg_],0.f)); \
            *(unsigned int*)(cb_ + row_ * 64 + ((wb_ & 48) ^ ((row_ & 3) << 4)) \
                             + (wb_ & 15)) = u_;                              \
        }                                                                     \
        bf16x8 a_ = *(const bf16x8*)(cb_ + col * 64 +                         \
                                     ((quad << 4) ^ ((col & 3) << 4)));       \
        m0_ = MF(a_, *(const bf16x8*)(Wm2L + p_ * 512 + lane * 8), m0_);      \
        m1_ = MF(a_, *(const bf16x8*)(Wm2L + (7 + p_) * 512 + lane * 8), m1_);\
    }                                                                         \
    {   /* leftover N-tile 12 (kt=6): cols 192..199 real, pad const in cP */  \
        const bf16* Wf_ = Wm1L + 24 * 512 + lane * 8;                         \
        bf16x8 b0_ = *(const bf16x8*)(Wf_);                                   \
        bf16x8 b1_ = *(const bf16x8*)(Wf_ + 512);                             \
        f32x4 acc_ = {0.f,0.f,0.f,0.f};                                       \
        acc_ = MF(P##A0, b0_, acc_);                                          \
        acc_ = MF(P##A1, b1_, acc_);                                          \
        if (col < 8) {                                                        \
            _Pragma("unroll")                                                 \
            for (int rg_ = 0; rg_ < 4; ++rg_) {                               \
                int row_ = row0 + rg_;                                        \
                *(bf16*)(cP + row_ * 64 + ((row_ & 3) << 4) + 2 * col) =      \
                    (bf16)fmaxf(acc_[rg_], 0.f);                              \
            }                                                                 \
        }                                                                     \
        bf16x8 a_ = *(const bf16x8*)(cP + col * 64 +                          \
                                     ((quad << 4) ^ ((col & 3) << 4)));       \
        m0_ = MF(a_, *(const bf16x8*)(Wm2L + 6 * 512 + lane * 8), m0_);       \
        m1_ = MF(a_, *(const bf16x8*)(Wm2L + 13 * 512 + lane * 8), m1_);      \
    }                                                                         \
    /* selector GEMM: diff[16x32] (rows 30/31 zero -> ew patch inert) */      \
    f32x4 dc0_ = {0.f,0.f,0.f,0.f}, dc1_ = {0.f,0.f,0.f,0.f};                 \
    dc0_ = MF(P##A0, *(const bf16x8*)(SelB + (size_t)0*512 + lane*8), dc0_);  \
    dc1_ = MF(P##A0, *(const bf16x8*)(SelB + (size_t)1*512 + lane*8), dc1_);  \
    dc0_ = MF(P##A1, *(const bf16x8*)(SelB + (size_t)2*512 + lane*8), dc0_);  \
    dc1_ = MF(P##A1, *(const bf16x8*)(SelB + (size_t)3*512 + lane*8), dc1_);  \
    dc0_ = MF(P##a2, *(const bf16x8*)(SelB + (size_t)4*512 + lane*8), dc0_);  \
    dc1_ = MF(P##a2, *(const bf16x8*)(SelB + (size_t)5*512 + lane*8), dc1_);  \
    dc0_ = MF(P##a3, *(const bf16x8*)(SelB + (size_t)6*512 + lane*8), dc0_);  \
    dc1_ = MF(P##a3, *(const bf16x8*)(SelB + (size_t)7*512 + lane*8), dc1_);  \
    /* md = m*diff -> chunkA -> GEMM3 A-frag */                               \
    _Pragma("unroll")                                                         \
    for (int rg_ = 0; rg_ < 4; ++rg_) {                                       \
        int row_ = row0 + rg_, wb_ = 4 * col;                                 \
        unsigned int u_ = (col == 15) ? pk_bf16(1.f, 0.f)                     \
                        : pk_bf16(m0_[rg_]*dc0_[rg_], m1_[rg_]*dc1_[rg_]);    \
        *(unsigned int*)(cA + row_ * 64 + ((wb_ & 48) ^ ((row_ & 3) << 4))    \
                         + (wb_ & 15)) = u_;                                  \
    }                                                                         \
    bf16x8 am_ = *(const bf16x8*)(cA + col * 64 +                             \
                                  ((quad << 4) ^ ((col & 3) << 4)));          \
    /* GEMM3: md[16x32] @ W2[32xN] -> msg */                                  \
    if (COUT == 30) {                                                         \
        f32x4 c0_ = {0.f,0.f,0.f,0.f}, c1_ = {0.f,0.f,0.f,0.f};               \
        c0_ = MF(am_, *(const bf16x8*)(W2B + lane*8), c0_);                   \
        c1_ = MF(am_, *(const bf16x8*)(W2B + 512 + lane*8), c1_);             \
        _Pragma("unroll")                                                     \
        for (int rg_ = 0; rg_ < 4; ++rg_)                                     \
            *(unsigned int*)(msg + (size_t)((EBASE) + row0 + rg_)*32 + 2*col) = \
                pk_bf16(c0_[rg_], c1_[rg_]);                                  \
    } else {                                                                  \
        /* COUT=1: compact msg1[e] — one 8B store per col==0 lane */          \
        f32x4 c0_ = {0.f,0.f,0.f,0.f};                                        \
        c0_ = MF(am_, *(const bf16x8*)(W2B + lane*8), c0_);                   \
        if (col == 0) {                                                       \
            union { bf16 h[4]; unsigned long long u; } pk4_;                  \
            _Pragma("unroll")                                                 \
            for (int rg_ = 0; rg_ < 4; ++rg_) pk4_.h[rg_] = (bf16)c0_[rg_];   \
            *(unsigned long long*)(msg + ((EBASE) + row0)) = pk4_.u;          \
        }                                                                     \
    }                                                                         \
} while (0)

template<int COUT>
__global__ __launch_bounds__(256, 3) void edge_mfma(
    const bf16* __restrict__ xc, const int4* __restrict__ edata,
    const bf16* __restrict__ Wm1B, const bf16* __restrict__ SelB,
    const bf16* __restrict__ Wm2B, const bf16* __restrict__ W2B,
    bf16* __restrict__ msg)
{
    // [0,13312): Wm1 26 frags; [13312,20480): Wm2 14 frags;
    // [20480,26624): 4 waves x 3 x 512 chunk buffers.  53248 B total.
    __shared__ __align__(16) bf16 smem[26624];
    bf16* Wm1L = smem;
    bf16* Wm2L = smem + 13312;

    const int tid = threadIdx.x, w = tid >> 6, lane = tid & 63;
    const int col = lane & 15, quad = lane >> 4, row0 = quad * 4;
    const int myrow = w * 16;
    const int blk = blockIdx.x * 256;             // 4 tiles x 64 edges

    // ---- issue all 4 edata loads FIRST (fly during staging) ----
    const int eoff = myrow + col;
    int4 ed0 = edata[blk + 0 * 64 + eoff];
    int4 ed1 = edata[blk + 1 * 64 + eoff];
    int4 ed2 = edata[blk + 2 * 64 + eoff];
    int4 ed3 = edata[blk + 3 * 64 + eoff];

    // ---- stage weights: 2560 x 16B chunks, 10 per thread ----
#pragma unroll
    for (int i = 0; i < 10; ++i) {
        int idx = tid + i * 256;
        bf16x8 v = (idx < 1664) ? *((const bf16x8*)Wm1B + idx)
                                : *((const bf16x8*)Wm2B + (idx - 1664));
        *((bf16x8*)smem + idx) = v;
    }
    __syncthreads();

    char* cbase = (char*)(smem + 20480 + w * 1536);
    char* cA = cbase;
    char* cB = cbase + 1024;
    char* cP = cbase + 2048;

    // cP pad slots 1..3 (global cols 200..223): slot1 elem0 = bm2 bias row
    // marker (1.0), rest 0. Written once; tiles only rewrite slot 0.
    if (lane < 48) {
        int r = lane / 3, s = 1 + (lane - r * 3);
        bf16x8 z = {};
        if (s == 1) z[0] = (bf16)1.f;
        *(bf16x8*)(cP + r * 64 + ((s << 4) ^ ((r & 3) << 4))) = z;
    }

    // ---- rolling 2-deep pipeline over 4 tiles ----
    bf16x8 pA0, pA1, pa2, pa3, qA0, qA1, qa2, qa3;
    LOAD_FRAGS(p, ed0);
    LOAD_FRAGS(q, ed1);

    COMPUTE_TILE(p, ed0.z, blk + 0 * 64 + myrow);
    LOAD_FRAGS(p, ed2);
    COMPUTE_TILE(q, ed1.z, blk + 1 * 64 + myrow);
    LOAD_FRAGS(q, ed3);
    COMPUTE_TILE(p, ed2.z, blk + 2 * 64 + myrow);
    COMPUTE_TILE(q, ed3.z, blk + 3 * 64 + myrow);
}

// ===========================================================================
// Fused aggregation + next node term. 16 lanes per node; width-16 shuffles;
// fma order identical to the original node_kernel -> numerically identical.
// Writes the merged xc row: hi (bf16 x) at cols [0,32), lo residual at [32,64).
// ===========================================================================
template<int CNEXT>
__global__ __launch_bounds__(256) void agg_fused(
    const bf16* __restrict__ msg, const int* __restrict__ offsets,
    const float* __restrict__ bufc,
    const float* __restrict__ W1n, const float* __restrict__ b1n,
    float* __restrict__ bufn,
    bf16* __restrict__ xc) {
    int gh = (blockIdx.x * 256 + threadIdx.x) >> 4;
    int lane = threadIdx.x & 15;
    int s0 = offsets[gh], s1 = offsets[gh + 1];
    float r0 = 0.f, r1 = 0.f;
    if (lane < 15) {
        float v0 = 0.f, v1 = 0.f;
        const unsigned int* mp =
            (const unsigned int*)(msg + (size_t)s0 * 32 + lane * 2);
        int cnt = s1 - s0, j = 0;
        for (; j + 4 <= cnt; j += 4) {
            unsigned int u0 = mp[(size_t)(j + 0) * 16];
            unsigned int u1 = mp[(size_t)(j + 1) * 16];
            unsigned int u2 = mp[(size_t)(j + 2) * 16];
            unsigned int u3 = mp[(size_t)(j + 3) * 16];
            union { unsigned int u; bf16 b[2]; } c0, c1, c2, c3;
            c0.u = u0; c1.u = u1; c2.u = u2; c3.u = u3;
            v0 += (float)c0.b[0]; v1 += (float)c0.b[1];
            v0 += (float)c1.b[0]; v1 += (float)c1.b[1];
            v0 += (float)c2.b[0]; v1 += (float)c2.b[1];
            v0 += (float)c3.b[0]; v1 += (float)c3.b[1];
        }
        for (; j < cnt; ++j) {
            union { unsigned int u; bf16 b[2]; } cv;
            cv.u = mp[(size_t)j * 16];
            v0 += (float)cv.b[0]; v1 += (float)cv.b[1];
        }
        float f0 = bufc[(size_t)gh * 30 + 2 * lane] + v0;
        float f1 = bufc[(size_t)gh * 30 + 2 * lane + 1] + v1;
        r0 = fmaxf(f0, 0.f);
        r1 = fmaxf(f1, 0.f);
        bf16 h0 = (bf16)r0, h1 = (bf16)r1;
        union { bf16 h[2]; unsigned int u; } hi;
        hi.h[0] = h0; hi.h[1] = h1;
        *(unsigned int*)(xc + (size_t)gh * 64 + 2 * lane) = hi.u;
        *(unsigned int*)(xc + (size_t)gh * 64 + 32 + 2 * lane) =
            pk_bf16(r0 - (float)h0, r1 - (float)h1);
    } else {
        *(unsigned int*)(xc + (size_t)gh * 64 + 30) = pk_bf16(1.f, 0.f);
        *(unsigned int*)(xc + (size_t)gh * 64 + 62) = 0u;
    }
    // ---- next node term (fma order == original node_kernel) ----
    if (CNEXT == 30) {
        float acc0 = 0.f, acc1 = 0.f;
        if (lane < 15) { acc0 = b1n[2 * lane]; acc1 = b1n[2 * lane + 1]; }
        for (int k2 = 0; k2 < 15; ++k2) {
            float rk0 = __shfl(r0, k2, 16);
            float rk1 = __shfl(r1, k2, 16);
            if (lane < 15) {
                const float* w0 = W1n + (2 * k2) * 30 + 2 * lane;
                const float* w1 = W1n + (2 * k2 + 1) * 30 + 2 * lane;
                acc0 = fmaf(rk0, w0[0], acc0);
                acc1 = fmaf(rk0, w0[1], acc1);
                acc0 = fmaf(rk1, w1[0], acc0);
                acc1 = fmaf(rk1, w1[1], acc1);
            }
        }
        if (lane < 15) {
            bufn[(size_t)gh * 30 + 2 * lane] = acc0;
            bufn[(size_t)gh * 30 + 2 * lane + 1] = acc1;
        }
    } else {
        float acc = b1n[0];
        for (int k2 = 0; k2 < 15; ++k2) {
            float rk0 = __shfl(r0, k2, 16);
            float rk1 = __shfl(r1, k2, 16);
            acc = fmaf(rk0, W1n[2 * k2], acc);
            acc = fmaf(rk1, W1n[2 * k2 + 1], acc);
        }
        if (lane == 0) bufn[gh] = acc;
    }
}

// Final aggregation, compact msg1[e]: out[gh] += sum (same lane->j order)
__global__ __launch_bounds__(256) void agg_last(const bf16* __restrict__ msg1,
                                                const int* __restrict__ offsets,
                                                float* __restrict__ out) {
    int gh = (blockIdx.x * 256 + threadIdx.x) >> 5;
    int lane = threadIdx.x & 31;
    int s0 = offsets[gh], s1 = offsets[gh + 1];
    float v = 0.f;
    for (int j = s0 + lane; j < s1; j += 32) v += (float)msg1[j];
#pragma unroll
    for (int o = 16; o > 0; o >>= 1) v += __shfl_xor(v, o);
    if (lane == 0) out[gh] += v;
}

// ===========================================================================
extern "C" void kernel_launch(void* const* d_in, const int* in_sizes, int n_in,
                              void* d_out, int out_size, void* d_ws, size_t ws_size,
                              hipStream_t stream) {
    const float* features = (const float*)d_in[0];
    const int*   edges    = (const int*)d_in[1];
    const float* ew       = (const float*)d_in[2];

    const float* W1_d  = (const float*)d_in[3];
    const float* b1_d  = (const float*)d_in[4];
    const float* Wm1_d = (const float*)d_in[5];
    const float* bm1_d = (const float*)d_in[6];
    const float* Wm2_d = (const float*)d_in[7];
    const float* bm2_d = (const float*)d_in[8];
    const float* W2_d  = (const float*)d_in[9];
    const float* b2_d  = (const float*)d_in[10];

    const float* W1_h  = (const float*)d_in[11];
    const float* b1_h  = (const float*)d_in[12];
    const float* Wm1_h = (const float*)d_in[13];
    const float* bm1_h = (const float*)d_in[14];
    const float* Wm2_h = (const float*)d_in[15];
    const float* bm2_h = (const float*)d_in[16];
    const float* W2_h  = (const float*)d_in[17];
    const float* b2_h  = (const float*)d_in[18];

    const float* W1_o  = (const float*)d_in[19];
    const float* b1_o  = (const float*)d_in[20];
    const float* Wm1_o = (const float*)d_in[21];
    const float* bm1_o = (const float*)d_in[22];
    const float* Wm2_o = (const float*)d_in[23];
    const float* bm2_o = (const float*)d_in[24];
    const float* W2_o  = (const float*)d_in[25];
    const float* b2_o  = (const float*)d_in[26];

    const int* src = edges;
    const int* dst = edges + N_EDGES;
    float* out = (float*)d_out;

    // ---- workspace carve-up ----
    char* p = (char*)d_ws;
    auto alloc = [&](size_t bytes) { char* r = p; p += (bytes + 63) & ~(size_t)63; return r; };
    float* bufA    = (float*)alloc((size_t)N_NODES * 30 * 4);
    float* bufB    = (float*)alloc((size_t)N_NODES * 30 * 4);
    bf16*  msg     = (bf16*) alloc((size_t)N_EDGES * 32 * 2);
    bf16*  xc      = (bf16*) alloc((size_t)N_NODES * 64 * 2);
    int*   counts  = (int*)  alloc((size_t)N_NODES * 4);
    int*   offsets = (int*)  alloc((size_t)(N_NODES + 1) * 4);
    int*   cursor  = (int*)  alloc((size_t)N_NODES * 4);
    int4*  edata   = (int4*) alloc((size_t)N_EDGES * 16);
    float* Wm1T_d  = (float*)alloc((size_t)C_MSG * 4 * 4);
    bf16*  Wm1B_h  = (bf16*) alloc((size_t)26 * 512 * 2);
    bf16*  Wm1B_o  = (bf16*) alloc((size_t)26 * 512 * 2);
    bf16*  Wm2B_h  = (bf16*) alloc((size_t)14 * 512 * 2);
    bf16*  Wm2B_o  = (bf16*) alloc((size_t)14 * 512 * 2);
    bf16*  W2B_h   = (bf16*) alloc((size_t)2 * 512 * 2);
    bf16*  W2B_o   = (bf16*) alloc((size_t)1 * 512 * 2);
    bf16*  SelB    = (bf16*) alloc((size_t)8 * 512 * 2);

    // ---- setup ----
    hipMemsetAsync(counts, 0, (size_t)N_NODES * 4, stream);
    setup_a<<<3507, 256, 0, stream>>>(dst, counts,
        Wm1_h, bm1_h, Wm1_o, bm1_o, Wm2_h, bm2_h, Wm2_o, bm2_o,
        W2_h, b2_h, W2_o, b2_o, Wm1_d,
        Wm1B_h, Wm1B_o, Wm2B_h, Wm2B_o, W2B_h, W2B_o, SelB, Wm1T_d,
        features, W1_d, b1_d, bufA);
    scan_kernel<<<(N_NODES + 255) / 256, 256, 0, stream>>>(counts, offsets, cursor);
    scatter_kernel<<<N_EDGES / 256, 256, 0, stream>>>(src, dst, ew, cursor, edata);

    dim3 tb(256);
    dim3 eb_mfma(N_EDGES / 256);   // 4 tiles of 64 edges per block
    dim3 eb_valu(N_EDGES / 256);
    dim3 ab16(N_NODES * 16 / 256);
    dim3 ab32(N_NODES * 32 / 256);

    // ---- layer d ----
    edge_d_kernel<<<eb_valu, tb, 0, stream>>>(features, edata, ew,
        Wm1T_d, bm1_d, Wm2_d, bm2_d, W2_d, b2_d, msg);
    agg_fused<30><<<ab16, tb, 0, stream>>>(msg, offsets, bufA, W1_h, b1_h, bufB, xc);

    // ---- h1 ----
    edge_mfma<30><<<eb_mfma, tb, 0, stream>>>(xc, edata,
        Wm1B_h, SelB, Wm2B_h, W2B_h, msg);
    agg_fused<30><<<ab16, tb, 0, stream>>>(msg, offsets, bufB, W1_h, b1_h, bufA, xc);

    // ---- h2 ----
    edge_mfma<30><<<eb_mfma, tb, 0, stream>>>(xc, edata,
        Wm1B_h, SelB, Wm2B_h, W2B_h, msg);
    agg_fused<30><<<ab16, tb, 0, stream>>>(msg, offsets, bufA, W1_h, b1_h, bufB, xc);

    // ---- h3 (next node term = output layer -> writes d_out) ----
    edge_mfma<30><<<eb_mfma, tb, 0, stream>>>(xc, edata,
        Wm1B_h, SelB, Wm2B_h, W2B_h, msg);
    agg_fused<1><<<ab16, tb, 0, stream>>>(msg, offsets, bufB, W1_o, b1_o, out, xc);

    // ---- output layer (compact msg1) ----
    edge_mfma<1><<<eb_mfma, tb, 0, stream>>>(xc, edata,
        Wm1B_o, SelB, Wm2B_o, W2B_o, msg);
    agg_last<<<ab32, tb, 0, stream>>>(msg, offsets, out);
}